// Round 4
// baseline (866.630 us; speedup 1.0000x reference)
//
#include <hip/hip_runtime.h>

#define N_NODES 4096
#define C_CH    128
#define E_ELEM  10
#define NP      4736          // padded sorted-node space (64-aligned per element)
#define TT      219           // 9 deg1 + 45 deg2 + 165 deg3 monomials
#define PSTRIDE (TT * 4)      // 876 floats per (e,c): [t][m], m0=L0, m1..3=L1
#define MAXCHUNK 32
#define CHUNK_J  512          // j-slots per k_poly block (256 thr x 2 nodes)

// ws layout (bytes):
//   0       hist[10]
//   64      pstart[11]      (64-aligned padded starts)
//   128     pcursor[10]
//   256     chunk_e[32]
//   512     chunk_j0[32]
//   768     chunk_end[32]
//   1024    jlist_p[4736]   (-1 = pad slot)
//   20480   elem[4096]
//   36864   S31[3465]   symmetrized U3_1  [m][t3][7]
//   50752   S30[825]    symmetrized U3_0  [t3][5]
//   54080   S21[405]    symmetrized U2_1  [m][t2][3]
//   55712   S20[90]     symmetrized U2_0  [t2][2]
//   57344   P[1280*876] per-(e,c) poly coeffs [ec][t][4]
//   4542464 bout[512*4736]  [c*4+slot][j]
#define WS_HIST    0
#define WS_PSTART  64
#define WS_PCUR    128
#define WS_CHE     256
#define WS_CHJ     512
#define WS_CHEND   768
#define WS_JLIST   1024
#define WS_ELEM    20480
#define WS_S31     36864
#define WS_S30     50752
#define WS_S21     54080
#define WS_S20     55712
#define WS_P       57344
#define WS_BOUT    4542464

__global__ void k_elem_hist(const float* __restrict__ attrs, int* __restrict__ elem,
                            int* __restrict__ hist, int* __restrict__ jlist) {
    int n = blockIdx.x * blockDim.x + threadIdx.x;
    if (n < NP) jlist[n] = -1;            // pad fill (runs before k_scatter)
    if (n >= N_NODES) return;
    const float* a = attrs + n * E_ELEM;
    float best = a[0];
    int e = 0;
#pragma unroll
    for (int k = 1; k < E_ELEM; ++k) {
        float v = a[k];
        if (v > best) { best = v; e = k; }
    }
    elem[n] = e;
    atomicAdd(&hist[e], 1);
}

__global__ void k_prefix(const int* __restrict__ hist, int* __restrict__ pstart,
                         int* __restrict__ pcursor, int* __restrict__ chE,
                         int* __restrict__ chJ, int* __restrict__ chEnd) {
    if (threadIdx.x != 0) return;
    int s = 0;
    for (int e = 0; e < E_ELEM; ++e) {
        pstart[e] = s;
        pcursor[e] = s;
        int plen = ((hist[e] + 63) >> 6) << 6;   // 64-align each element range
        s += plen;
    }
    pstart[E_ELEM] = s;
    int ci = 0;
    for (int e = 0; e < E_ELEM; ++e) {
        int base = pstart[e], end = pstart[e + 1];
        for (int ofs = base; ofs < end; ofs += CHUNK_J) {
            chE[ci] = e;
            chJ[ci] = ofs;
            chEnd[ci] = end;
            ++ci;
        }
    }
    for (; ci < MAXCHUNK; ++ci) chE[ci] = -1;
}

__global__ void k_scatter(const int* __restrict__ elem, int* __restrict__ pcursor,
                          int* __restrict__ jlist) {
    int n = blockIdx.x * blockDim.x + threadIdx.x;
    if (n >= N_NODES) return;
    int e = elem[n];
    int pos = atomicAdd(&pcursor[e], 1);
    jlist[pos] = n;
}

__device__ __forceinline__ void t3_decode(int t, int& a, int& b, int& i) {
    int cnt = 0;
    for (int aa = 0; aa < 9; ++aa)
        for (int bb = aa; bb < 9; ++bb) {
            int len = 9 - bb;
            if (t < cnt + len) { a = aa; b = bb; i = bb + (t - cnt); return; }
            cnt += len;
        }
    a = b = i = 8;
}

__device__ __forceinline__ void t2_decode(int t, int& a, int& b) {
    int cnt = 0;
    for (int aa = 0; aa < 9; ++aa) {
        int len = 9 - aa;
        if (t < cnt + len) { a = aa; b = aa + (t - cnt); return; }
        cnt += len;
    }
    a = b = 8;
}

// Symmetrize U tensors over monomial multisets — parallel, 4785 work items.
__global__ void k_sym(const float* __restrict__ U3_1, const float* __restrict__ U3_0,
                      const float* __restrict__ U2_1, const float* __restrict__ U2_0,
                      float* __restrict__ S31, float* __restrict__ S30,
                      float* __restrict__ S21, float* __restrict__ S20) {
    int q = blockIdx.x * blockDim.x + threadIdx.x;
    if (q < 3465) {                                 // S31 [m][t][p], p=7
        int m = q / 1155, r = q % 1155, t = r / 7, p = r % 7;
        int a, b, i;
        t3_decode(t, a, b, i);
#define U31(X, Y, Z) U3_1[((((m * 9 + (X)) * 9 + (Y)) * 9 + (Z)) * 7) + p]
        float s = U31(a, b, i);
        if (a == b && b == i) {}
        else if (a == b) s += U31(a, i, a) + U31(i, a, a);
        else if (b == i) s += U31(b, a, b) + U31(b, b, a);
        else s += U31(a, i, b) + U31(b, a, i) + U31(b, i, a) + U31(i, a, b) + U31(i, b, a);
#undef U31
        S31[q] = s;
        return;
    }
    q -= 3465;
    if (q < 825) {                                  // S30 [t][p], p=5
        int t = q / 5, p = q % 5;
        int a, b, i;
        t3_decode(t, a, b, i);
#define U30(X, Y, Z) U3_0[((((X) * 9 + (Y)) * 9 + (Z)) * 5) + p]
        float s = U30(a, b, i);
        if (a == b && b == i) {}
        else if (a == b) s += U30(a, i, a) + U30(i, a, a);
        else if (b == i) s += U30(b, a, b) + U30(b, b, a);
        else s += U30(a, i, b) + U30(b, a, i) + U30(b, i, a) + U30(i, a, b) + U30(i, b, a);
#undef U30
        S30[q] = s;
        return;
    }
    q -= 825;
    if (q < 405) {                                  // S21 [m][t][p], p=3
        int m = q / 135, r = q % 135, t = r / 3, p = r % 3;
        int a, b;
        t2_decode(t, a, b);
        float s = U2_1[(((m * 9 + a) * 9 + b) * 3) + p];
        if (a != b) s += U2_1[(((m * 9 + b) * 9 + a) * 3) + p];
        S21[q] = s;
        return;
    }
    q -= 405;
    if (q < 90) {                                   // S20 [t][p], p=2
        int t = q / 2, p = q % 2;
        int a, b;
        t2_decode(t, a, b);
        float s = U2_0[((a * 9 + b) * 2) + p];
        if (a != b) s += U2_0[((b * 9 + a) * 2) + p];
        S20[q] = s;
    }
}

// Fold element weights into symmetrized basis: P[e*128+c][t][m]
__global__ __launch_bounds__(128) void k_fold(
    const float* __restrict__ S31, const float* __restrict__ S30,
    const float* __restrict__ S21, const float* __restrict__ S20,
    const float* __restrict__ U1_1, const float* __restrict__ U1_0,
    const float* __restrict__ W3_1, const float* __restrict__ W3_0,
    const float* __restrict__ W2_1, const float* __restrict__ W2_0,
    const float* __restrict__ W1_1, const float* __restrict__ W1_0,
    float* __restrict__ P) {
    int e = blockIdx.x >> 7;
    int c = blockIdx.x & 127;
    float* Pout = P + (size_t)blockIdx.x * PSTRIDE;
    for (int q = threadIdx.x; q < PSTRIDE; q += 128) {
        int t = q >> 2, m = q & 3;
        float v;
        if (t < 9) {
            int a = t;
            v = (m == 0) ? U1_0[a] * W1_0[e * C_CH + c]
                         : U1_1[(m - 1) * 9 + a] * W1_1[e * C_CH + c];
        } else if (t < 54) {
            int t2 = t - 9;
            float s = 0.f;
            if (m == 0) {
#pragma unroll
                for (int p = 0; p < 2; ++p)
                    s = fmaf(S20[t2 * 2 + p], W2_0[(e * 2 + p) * C_CH + c], s);
            } else {
#pragma unroll
                for (int p = 0; p < 3; ++p)
                    s = fmaf(S21[((m - 1) * 45 + t2) * 3 + p], W2_1[(e * 3 + p) * C_CH + c], s);
            }
            v = s;
        } else {
            int t3 = t - 54;
            float s = 0.f;
            if (m == 0) {
#pragma unroll
                for (int p = 0; p < 5; ++p)
                    s = fmaf(S30[t3 * 5 + p], W3_0[(e * 5 + p) * C_CH + c], s);
            } else {
#pragma unroll
                for (int p = 0; p < 7; ++p)
                    s = fmaf(S31[((m - 1) * 165 + t3) * 7 + p], W3_1[(e * 7 + p) * C_CH + c], s);
            }
            v = s;
        }
        Pout[q] = v;
    }
}

// Evaluate the 219-monomial cubic for NN nodes from LDS-staged coefficients.
// sched_barrier(0) after each (a,b) group: <=10 float4 LDS loads in flight,
// live set ~90 VGPR. amdgpu_waves_per_eu(4,4) on the caller pins the register
// allocator to the 128-VGPR budget so it cannot spill-for-occupancy (round 3:
// RA targeted 64 VGPR and generated 1.9 GB of scratch traffic).
template <int NN>
__device__ __forceinline__ void poly_eval(const float* __restrict__ sP,
                                          const float (&xv)[NN][9], float (&acc)[NN][4]) {
    const float* p1 = sP;
    const float* p2 = sP + 9 * 4;
    const float* p3 = sP + 54 * 4;
    int i2 = 0, i3 = 0;
#pragma unroll
    for (int a = 0; a < 9; ++a) {
        float4 q1 = *(const float4*)(p1 + a * 4);
#pragma unroll
        for (int u = 0; u < NN; ++u) {
            float xa = xv[u][a];
            acc[u][0] = fmaf(q1.x, xa, acc[u][0]);
            acc[u][1] = fmaf(q1.y, xa, acc[u][1]);
            acc[u][2] = fmaf(q1.z, xa, acc[u][2]);
            acc[u][3] = fmaf(q1.w, xa, acc[u][3]);
        }
        __builtin_amdgcn_sched_barrier(0);
#pragma unroll
        for (int b = a; b < 9; ++b) {
            float m2[NN];
            float4 q2 = *(const float4*)(p2 + i2 * 4);
            ++i2;
#pragma unroll
            for (int u = 0; u < NN; ++u) {
                m2[u] = xv[u][a] * xv[u][b];
                acc[u][0] = fmaf(q2.x, m2[u], acc[u][0]);
                acc[u][1] = fmaf(q2.y, m2[u], acc[u][1]);
                acc[u][2] = fmaf(q2.z, m2[u], acc[u][2]);
                acc[u][3] = fmaf(q2.w, m2[u], acc[u][3]);
            }
#pragma unroll
            for (int i = b; i < 9; ++i) {
                float4 q3 = *(const float4*)(p3 + i3 * 4);
                ++i3;
#pragma unroll
                for (int u = 0; u < NN; ++u) {
                    float m3 = m2[u] * xv[u][i];
                    acc[u][0] = fmaf(q3.x, m3, acc[u][0]);
                    acc[u][1] = fmaf(q3.y, m3, acc[u][1]);
                    acc[u][2] = fmaf(q3.z, m3, acc[u][2]);
                    acc[u][3] = fmaf(q3.w, m3, acc[u][3]);
                }
            }
            __builtin_amdgcn_sched_barrier(0);
        }
    }
}

__global__ __launch_bounds__(256)
__attribute__((amdgpu_waves_per_eu(4, 4))) void k_poly(
    const float* __restrict__ x, const int* __restrict__ jlist,
    const int* __restrict__ chE, const int* __restrict__ chJ,
    const int* __restrict__ chEnd, const float* __restrict__ P,
    float* __restrict__ bout) {
    int ci = blockIdx.y;
    int e = chE[ci];
    if (e < 0) return;
    e = __builtin_amdgcn_readfirstlane(e);   // keep coefficient addressing scalar
    int c = blockIdx.x;
    __shared__ __align__(16) float sP[PSTRIDE];
    const float* Pg = P + (size_t)(e * C_CH + c) * PSTRIDE;
    for (int t = threadIdx.x; t < PSTRIDE; t += 256) sP[t] = Pg[t];
    __syncthreads();

    const int end = chEnd[ci];
    const int jA = chJ[ci] + threadIdx.x;
    const int jB = jA + 256;
    const int nAr = (jA < end) ? jlist[jA] : -1;
    const int nBr = (jB < end) ? jlist[jB] : -1;
    const bool vA = nAr >= 0, vB = nBr >= 0;
    const int nA = vA ? nAr : 0;
    const int nB = vB ? nBr : 0;
    const float* pA = x + (size_t)(nA * C_CH + c) * 9;
    const float* pB = x + (size_t)(nB * C_CH + c) * 9;
    float xv[2][9];
    float acc[2][4] = {};
#pragma unroll
    for (int i = 0; i < 9; ++i) { xv[0][i] = pA[i]; xv[1][i] = pB[i]; }
    poly_eval<2>(sP, xv, acc);
    if (vA) {
#pragma unroll
        for (int m = 0; m < 4; ++m) bout[(size_t)(c * 4 + m) * NP + jA] = acc[0][m];
    }
    if (vB) {
#pragma unroll
        for (int m = 0; m < 4; ++m) bout[(size_t)(c * 4 + m) * NP + jB] = acc[1][m];
    }
}

__global__ __launch_bounds__(512) void k_linear(
    const float* __restrict__ bout, const int* __restrict__ jlist,
    const float* __restrict__ Wl0, const float* __restrict__ Wl1,
    const float* __restrict__ sc, float* __restrict__ out) {
    const int col = threadIdx.x;
    const int jbase = blockIdx.x * 16;
    int d, slot;
    const float* Wl;
    if (col < 128) { d = col; slot = 0; Wl = Wl0; }
    else {
        int q = col - 128;
        d = q / 3;
        slot = 1 + q % 3;
        Wl = Wl1;
    }
    float acc[16];
#pragma unroll
    for (int q = 0; q < 16; ++q) acc[q] = 0.f;

    for (int cc = 0; cc < C_CH; ++cc) {
        float w = Wl[cc * C_CH + d];
        const float4* bp =
            reinterpret_cast<const float4*>(bout + (size_t)(cc * 4 + slot) * NP + jbase);
#pragma unroll
        for (int q = 0; q < 4; ++q) {
            float4 v = bp[q];
            acc[q * 4 + 0] = fmaf(w, v.x, acc[q * 4 + 0]);
            acc[q * 4 + 1] = fmaf(w, v.y, acc[q * 4 + 1]);
            acc[q * 4 + 2] = fmaf(w, v.z, acc[q * 4 + 2]);
            acc[q * 4 + 3] = fmaf(w, v.w, acc[q * 4 + 3]);
        }
    }

    const float inv = 0.08838834764831845f;  // 1/sqrt(128)
#pragma unroll
    for (int jj = 0; jj < 16; ++jj) {
        int n = jlist[jbase + jj];
        if (n >= 0) out[n * 512 + col] = fmaf(acc[jj], inv, sc[n * 512 + col]);
    }
}

extern "C" void kernel_launch(void* const* d_in, const int* in_sizes, int n_in,
                              void* d_out, int out_size, void* d_ws, size_t ws_size,
                              hipStream_t stream) {
    const float* x     = (const float*)d_in[0];
    const float* sc    = (const float*)d_in[1];
    const float* attrs = (const float*)d_in[2];
    const float* U3_0 = (const float*)d_in[3];
    const float* U2_0 = (const float*)d_in[4];
    const float* U1_0 = (const float*)d_in[5];
    const float* W3_0 = (const float*)d_in[6];
    const float* W2_0 = (const float*)d_in[7];
    const float* W1_0 = (const float*)d_in[8];
    const float* Wl0  = (const float*)d_in[9];
    const float* U3_1 = (const float*)d_in[10];
    const float* U2_1 = (const float*)d_in[11];
    const float* U1_1 = (const float*)d_in[12];
    const float* W3_1 = (const float*)d_in[13];
    const float* W2_1 = (const float*)d_in[14];
    const float* W1_1 = (const float*)d_in[15];
    const float* Wl1  = (const float*)d_in[16];

    char* ws = (char*)d_ws;
    int* hist    = (int*)(ws + WS_HIST);
    int* pstart  = (int*)(ws + WS_PSTART);
    int* pcursor = (int*)(ws + WS_PCUR);
    int* chE     = (int*)(ws + WS_CHE);
    int* chJ     = (int*)(ws + WS_CHJ);
    int* chEnd   = (int*)(ws + WS_CHEND);
    int* jlist   = (int*)(ws + WS_JLIST);
    int* elem    = (int*)(ws + WS_ELEM);
    float* S31   = (float*)(ws + WS_S31);
    float* S30   = (float*)(ws + WS_S30);
    float* S21   = (float*)(ws + WS_S21);
    float* S20   = (float*)(ws + WS_S20);
    float* P     = (float*)(ws + WS_P);
    float* bout  = (float*)(ws + WS_BOUT);

    hipMemsetAsync(hist, 0, E_ELEM * sizeof(int), stream);
    k_elem_hist<<<(NP + 255) / 256, 256, 0, stream>>>(attrs, elem, hist, jlist);
    k_prefix<<<1, 64, 0, stream>>>(hist, pstart, pcursor, chE, chJ, chEnd);
    k_scatter<<<16, 256, 0, stream>>>(elem, pcursor, jlist);
    k_sym<<<19, 256, 0, stream>>>(U3_1, U3_0, U2_1, U2_0, S31, S30, S21, S20);
    k_fold<<<1280, 128, 0, stream>>>(S31, S30, S21, S20, U1_1, U1_0,
                                     W3_1, W3_0, W2_1, W2_0, W1_1, W1_0, P);
    k_poly<<<dim3(128, MAXCHUNK), 256, 0, stream>>>(x, jlist, chE, chJ, chEnd, P, bout);
    k_linear<<<(NP / 16), 512, 0, stream>>>(bout, jlist, Wl0, Wl1, sc, (float*)d_out);
}

// Round 5
// 240.126 us; speedup vs baseline: 3.6091x; 3.6091x over previous
//
#include <hip/hip_runtime.h>

#define N_NODES 4096
#define C_CH    128
#define E_ELEM  10
#define NP      4736          // padded sorted-node space (64-aligned per element)
#define TT      219           // 9 deg1 + 45 deg2 + 165 deg3 monomials
#define PSTRIDE (TT * 4)      // 876 floats per (e,c): [t][m], m0=L0, m1..3=L1
#define MAXCHUNK 32
#define CHUNK_J  256          // j-slots per k_poly block (256 thr x 1 node)

// ws layout (bytes):
#define WS_HIST    0
#define WS_PSTART  64
#define WS_PCUR    128
#define WS_CHE     256
#define WS_CHJ     512
#define WS_CHEND   768
#define WS_JLIST   1024        // int[4736]
#define WS_ELEM    20480       // int[4096]
#define WS_RANK    36864       // int[4096]
#define WS_S31     53248       // float[3465]
#define WS_S30     67136       // float[825]
#define WS_S21     70464       // float[405]
#define WS_S20     72128       // float[90]
#define WS_P       72704       // float[1280*876] = 4485120 B
#define WS_BOUT    4557824     // float[512*4736] = 9699328 B
#define WS_XS      14257152    // float[128*4736*9] = 21823488 B (optional)
#define WS_XS_END  36080640ull

__global__ void k_elem_hist(const float* __restrict__ attrs, int* __restrict__ elem,
                            int* __restrict__ hist, int* __restrict__ jlist) {
    int n = blockIdx.x * blockDim.x + threadIdx.x;
    if (n < NP) jlist[n] = -1;            // pad fill (runs before k_scatter)
    if (n >= N_NODES) return;
    const float* a = attrs + n * E_ELEM;
    float best = a[0];
    int e = 0;
#pragma unroll
    for (int k = 1; k < E_ELEM; ++k) {
        float v = a[k];
        if (v > best) { best = v; e = k; }
    }
    elem[n] = e;
    atomicAdd(&hist[e], 1);
}

__global__ void k_prefix(const int* __restrict__ hist, int* __restrict__ pstart,
                         int* __restrict__ pcursor, int* __restrict__ chE,
                         int* __restrict__ chJ, int* __restrict__ chEnd) {
    if (threadIdx.x != 0) return;
    int s = 0;
    for (int e = 0; e < E_ELEM; ++e) {
        pstart[e] = s;
        pcursor[e] = s;
        int plen = ((hist[e] + 63) >> 6) << 6;   // 64-align each element range
        s += plen;
    }
    pstart[E_ELEM] = s;
    int ci = 0;
    for (int e = 0; e < E_ELEM; ++e) {
        int base = pstart[e], end = pstart[e + 1];
        for (int ofs = base; ofs < end; ofs += CHUNK_J) {
            chE[ci] = e;
            chJ[ci] = ofs;
            chEnd[ci] = end;
            ++ci;
        }
    }
    for (; ci < MAXCHUNK; ++ci) chE[ci] = -1;
}

__global__ void k_scatter(const int* __restrict__ elem, int* __restrict__ pcursor,
                          int* __restrict__ jlist, int* __restrict__ rank) {
    int n = blockIdx.x * blockDim.x + threadIdx.x;
    if (n >= N_NODES) return;
    int e = elem[n];
    int pos = atomicAdd(&pcursor[e], 1);
    jlist[pos] = n;
    rank[n] = pos;
}

// Transpose x[n][c][i] -> xs[c][j][i] (sorted-j space). Reads fully coalesced.
__global__ void k_xpose(const float* __restrict__ x, const int* __restrict__ rank,
                        float* __restrict__ xs) {
    int tid = blockIdx.x * blockDim.x + threadIdx.x;
    if (tid >= N_NODES * C_CH * 9) return;
    int n = tid / (C_CH * 9);
    int q = tid - n * (C_CH * 9);
    int c = q / 9;
    int i = q - c * 9;
    xs[((size_t)c * NP + rank[n]) * 9 + i] = x[tid];
}

__device__ __forceinline__ void t3_decode(int t, int& a, int& b, int& i) {
    int cnt = 0;
    for (int aa = 0; aa < 9; ++aa)
        for (int bb = aa; bb < 9; ++bb) {
            int len = 9 - bb;
            if (t < cnt + len) { a = aa; b = bb; i = bb + (t - cnt); return; }
            cnt += len;
        }
    a = b = i = 8;
}

__device__ __forceinline__ void t2_decode(int t, int& a, int& b) {
    int cnt = 0;
    for (int aa = 0; aa < 9; ++aa) {
        int len = 9 - aa;
        if (t < cnt + len) { a = aa; b = aa + (t - cnt); return; }
        cnt += len;
    }
    a = b = 8;
}

// Symmetrize U tensors over monomial multisets — parallel, 4785 work items.
__global__ void k_sym(const float* __restrict__ U3_1, const float* __restrict__ U3_0,
                      const float* __restrict__ U2_1, const float* __restrict__ U2_0,
                      float* __restrict__ S31, float* __restrict__ S30,
                      float* __restrict__ S21, float* __restrict__ S20) {
    int q = blockIdx.x * blockDim.x + threadIdx.x;
    if (q < 3465) {                                 // S31 [m][t][p], p=7
        int m = q / 1155, r = q % 1155, t = r / 7, p = r % 7;
        int a, b, i;
        t3_decode(t, a, b, i);
#define U31(X, Y, Z) U3_1[((((m * 9 + (X)) * 9 + (Y)) * 9 + (Z)) * 7) + p]
        float s = U31(a, b, i);
        if (a == b && b == i) {}
        else if (a == b) s += U31(a, i, a) + U31(i, a, a);
        else if (b == i) s += U31(b, a, b) + U31(b, b, a);
        else s += U31(a, i, b) + U31(b, a, i) + U31(b, i, a) + U31(i, a, b) + U31(i, b, a);
#undef U31
        S31[q] = s;
        return;
    }
    q -= 3465;
    if (q < 825) {                                  // S30 [t][p], p=5
        int t = q / 5, p = q % 5;
        int a, b, i;
        t3_decode(t, a, b, i);
#define U30(X, Y, Z) U3_0[((((X) * 9 + (Y)) * 9 + (Z)) * 5) + p]
        float s = U30(a, b, i);
        if (a == b && b == i) {}
        else if (a == b) s += U30(a, i, a) + U30(i, a, a);
        else if (b == i) s += U30(b, a, b) + U30(b, b, a);
        else s += U30(a, i, b) + U30(b, a, i) + U30(b, i, a) + U30(i, a, b) + U30(i, b, a);
#undef U30
        S30[q] = s;
        return;
    }
    q -= 825;
    if (q < 405) {                                  // S21 [m][t][p], p=3
        int m = q / 135, r = q % 135, t = r / 3, p = r % 3;
        int a, b;
        t2_decode(t, a, b);
        float s = U2_1[(((m * 9 + a) * 9 + b) * 3) + p];
        if (a != b) s += U2_1[(((m * 9 + b) * 9 + a) * 3) + p];
        S21[q] = s;
        return;
    }
    q -= 405;
    if (q < 90) {                                   // S20 [t][p], p=2
        int t = q / 2, p = q % 2;
        int a, b;
        t2_decode(t, a, b);
        float s = U2_0[((a * 9 + b) * 2) + p];
        if (a != b) s += U2_0[((b * 9 + a) * 2) + p];
        S20[q] = s;
    }
}

// Fold element weights into symmetrized basis: P[e*128+c][t][m]
__global__ __launch_bounds__(128) void k_fold(
    const float* __restrict__ S31, const float* __restrict__ S30,
    const float* __restrict__ S21, const float* __restrict__ S20,
    const float* __restrict__ U1_1, const float* __restrict__ U1_0,
    const float* __restrict__ W3_1, const float* __restrict__ W3_0,
    const float* __restrict__ W2_1, const float* __restrict__ W2_0,
    const float* __restrict__ W1_1, const float* __restrict__ W1_0,
    float* __restrict__ P) {
    int e = blockIdx.x >> 7;
    int c = blockIdx.x & 127;
    float* Pout = P + (size_t)blockIdx.x * PSTRIDE;
    for (int q = threadIdx.x; q < PSTRIDE; q += 128) {
        int t = q >> 2, m = q & 3;
        float v;
        if (t < 9) {
            int a = t;
            v = (m == 0) ? U1_0[a] * W1_0[e * C_CH + c]
                         : U1_1[(m - 1) * 9 + a] * W1_1[e * C_CH + c];
        } else if (t < 54) {
            int t2 = t - 9;
            float s = 0.f;
            if (m == 0) {
#pragma unroll
                for (int p = 0; p < 2; ++p)
                    s = fmaf(S20[t2 * 2 + p], W2_0[(e * 2 + p) * C_CH + c], s);
            } else {
#pragma unroll
                for (int p = 0; p < 3; ++p)
                    s = fmaf(S21[((m - 1) * 45 + t2) * 3 + p], W2_1[(e * 3 + p) * C_CH + c], s);
            }
            v = s;
        } else {
            int t3 = t - 54;
            float s = 0.f;
            if (m == 0) {
#pragma unroll
                for (int p = 0; p < 5; ++p)
                    s = fmaf(S30[t3 * 5 + p], W3_0[(e * 5 + p) * C_CH + c], s);
            } else {
#pragma unroll
                for (int p = 0; p < 7; ++p)
                    s = fmaf(S31[((m - 1) * 165 + t3) * 7 + p], W3_1[(e * 7 + p) * C_CH + c], s);
            }
            v = s;
        }
        Pout[q] = v;
    }
}

// 219-monomial cubic, ONE node-channel per thread. Live set ~60 VGPR -> fits
// the RA's 64-VGPR/8-wave target with zero spill (NN=2 at ~95 regs spilled
// 1.9 GB in rounds 3-4). sched_barrier(0) per (a,b) group keeps <=10 float4
// LDS loads in flight.
__device__ __forceinline__ void poly_eval1(const float* __restrict__ sP,
                                           const float (&xv)[9], float (&acc)[4]) {
    const float* p1 = sP;
    const float* p2 = sP + 9 * 4;
    const float* p3 = sP + 54 * 4;
    int i2 = 0, i3 = 0;
#pragma unroll
    for (int a = 0; a < 9; ++a) {
        float4 q1 = *(const float4*)(p1 + a * 4);
        float xa = xv[a];
        acc[0] = fmaf(q1.x, xa, acc[0]);
        acc[1] = fmaf(q1.y, xa, acc[1]);
        acc[2] = fmaf(q1.z, xa, acc[2]);
        acc[3] = fmaf(q1.w, xa, acc[3]);
        __builtin_amdgcn_sched_barrier(0);
#pragma unroll
        for (int b = a; b < 9; ++b) {
            float4 q2 = *(const float4*)(p2 + i2 * 4);
            ++i2;
            float m2 = xv[a] * xv[b];
            acc[0] = fmaf(q2.x, m2, acc[0]);
            acc[1] = fmaf(q2.y, m2, acc[1]);
            acc[2] = fmaf(q2.z, m2, acc[2]);
            acc[3] = fmaf(q2.w, m2, acc[3]);
#pragma unroll
            for (int i = b; i < 9; ++i) {
                float4 q3 = *(const float4*)(p3 + i3 * 4);
                ++i3;
                float m3 = m2 * xv[i];
                acc[0] = fmaf(q3.x, m3, acc[0]);
                acc[1] = fmaf(q3.y, m3, acc[1]);
                acc[2] = fmaf(q3.z, m3, acc[2]);
                acc[3] = fmaf(q3.w, m3, acc[3]);
            }
            __builtin_amdgcn_sched_barrier(0);
        }
    }
}

template <bool XS>
__global__ __launch_bounds__(256) void k_poly(
    const float* __restrict__ xsrc, const int* __restrict__ jlist,
    const int* __restrict__ chE, const int* __restrict__ chJ,
    const int* __restrict__ chEnd, const float* __restrict__ P,
    float* __restrict__ bout) {
    int ci = blockIdx.y;
    int e = chE[ci];
    if (e < 0) return;
    e = __builtin_amdgcn_readfirstlane(e);
    int c = blockIdx.x;
    __shared__ __align__(16) float sP[PSTRIDE];
    const float* Pg = P + (size_t)(e * C_CH + c) * PSTRIDE;
    for (int t = threadIdx.x; t < PSTRIDE; t += 256) sP[t] = Pg[t];
    __syncthreads();

    const int end = chEnd[ci];
    const int j = chJ[ci] + threadIdx.x;
    if (j >= end) return;

    float xv[9];
    bool valid = true;
    if (XS) {
        // coalesced: wave reads 64*36 B contiguous (pad slots read stale
        // data -> garbage bout, masked in k_linear)
        const float* px = xsrc + ((size_t)c * NP + j) * 9;
#pragma unroll
        for (int i = 0; i < 9; ++i) xv[i] = px[i];
    } else {
        int n = jlist[j];
        valid = n >= 0;
        const float* px = xsrc + (size_t)((valid ? n : 0) * C_CH + c) * 9;
#pragma unroll
        for (int i = 0; i < 9; ++i) xv[i] = px[i];
    }
    float acc[4] = {};
    poly_eval1(sP, xv, acc);
    if (valid) {
#pragma unroll
        for (int m = 0; m < 4; ++m) bout[(size_t)(c * 4 + m) * NP + j] = acc[m];
    }
}

__global__ __launch_bounds__(512) void k_linear(
    const float* __restrict__ bout, const int* __restrict__ jlist,
    const float* __restrict__ Wl0, const float* __restrict__ Wl1,
    const float* __restrict__ sc, float* __restrict__ out) {
    const int col = threadIdx.x;
    const int jbase = blockIdx.x * 16;
    int d, slot;
    const float* Wl;
    if (col < 128) { d = col; slot = 0; Wl = Wl0; }
    else {
        int q = col - 128;
        d = q / 3;
        slot = 1 + q % 3;
        Wl = Wl1;
    }
    float acc[16];
#pragma unroll
    for (int q = 0; q < 16; ++q) acc[q] = 0.f;

    for (int cc = 0; cc < C_CH; ++cc) {
        float w = Wl[cc * C_CH + d];
        const float4* bp =
            reinterpret_cast<const float4*>(bout + (size_t)(cc * 4 + slot) * NP + jbase);
#pragma unroll
        for (int q = 0; q < 4; ++q) {
            float4 v = bp[q];
            acc[q * 4 + 0] = fmaf(w, v.x, acc[q * 4 + 0]);
            acc[q * 4 + 1] = fmaf(w, v.y, acc[q * 4 + 1]);
            acc[q * 4 + 2] = fmaf(w, v.z, acc[q * 4 + 2]);
            acc[q * 4 + 3] = fmaf(w, v.w, acc[q * 4 + 3]);
        }
    }

    const float inv = 0.08838834764831845f;  // 1/sqrt(128)
#pragma unroll
    for (int jj = 0; jj < 16; ++jj) {
        int n = jlist[jbase + jj];
        if (n >= 0) out[n * 512 + col] = fmaf(acc[jj], inv, sc[n * 512 + col]);
    }
}

extern "C" void kernel_launch(void* const* d_in, const int* in_sizes, int n_in,
                              void* d_out, int out_size, void* d_ws, size_t ws_size,
                              hipStream_t stream) {
    const float* x     = (const float*)d_in[0];
    const float* sc    = (const float*)d_in[1];
    const float* attrs = (const float*)d_in[2];
    const float* U3_0 = (const float*)d_in[3];
    const float* U2_0 = (const float*)d_in[4];
    const float* U1_0 = (const float*)d_in[5];
    const float* W3_0 = (const float*)d_in[6];
    const float* W2_0 = (const float*)d_in[7];
    const float* W1_0 = (const float*)d_in[8];
    const float* Wl0  = (const float*)d_in[9];
    const float* U3_1 = (const float*)d_in[10];
    const float* U2_1 = (const float*)d_in[11];
    const float* U1_1 = (const float*)d_in[12];
    const float* W3_1 = (const float*)d_in[13];
    const float* W2_1 = (const float*)d_in[14];
    const float* W1_1 = (const float*)d_in[15];
    const float* Wl1  = (const float*)d_in[16];

    char* ws = (char*)d_ws;
    int* hist    = (int*)(ws + WS_HIST);
    int* pstart  = (int*)(ws + WS_PSTART);
    int* pcursor = (int*)(ws + WS_PCUR);
    int* chE     = (int*)(ws + WS_CHE);
    int* chJ     = (int*)(ws + WS_CHJ);
    int* chEnd   = (int*)(ws + WS_CHEND);
    int* jlist   = (int*)(ws + WS_JLIST);
    int* elem    = (int*)(ws + WS_ELEM);
    int* rank    = (int*)(ws + WS_RANK);
    float* S31   = (float*)(ws + WS_S31);
    float* S30   = (float*)(ws + WS_S30);
    float* S21   = (float*)(ws + WS_S21);
    float* S20   = (float*)(ws + WS_S20);
    float* P     = (float*)(ws + WS_P);
    float* bout  = (float*)(ws + WS_BOUT);
    float* xs    = (float*)(ws + WS_XS);
    const bool use_xs = (ws_size >= WS_XS_END);

    hipMemsetAsync(hist, 0, E_ELEM * sizeof(int), stream);
    k_elem_hist<<<(NP + 255) / 256, 256, 0, stream>>>(attrs, elem, hist, jlist);
    k_prefix<<<1, 64, 0, stream>>>(hist, pstart, pcursor, chE, chJ, chEnd);
    k_scatter<<<16, 256, 0, stream>>>(elem, pcursor, jlist, rank);
    k_sym<<<19, 256, 0, stream>>>(U3_1, U3_0, U2_1, U2_0, S31, S30, S21, S20);
    k_fold<<<1280, 128, 0, stream>>>(S31, S30, S21, S20, U1_1, U1_0,
                                     W3_1, W3_0, W2_1, W2_0, W1_1, W1_0, P);
    if (use_xs) {
        k_xpose<<<(N_NODES * C_CH * 9 + 255) / 256, 256, 0, stream>>>(x, rank, xs);
        k_poly<true><<<dim3(128, MAXCHUNK), 256, 0, stream>>>(xs, jlist, chE, chJ,
                                                              chEnd, P, bout);
    } else {
        k_poly<false><<<dim3(128, MAXCHUNK), 256, 0, stream>>>(x, jlist, chE, chJ,
                                                               chEnd, P, bout);
    }
    k_linear<<<(NP / 16), 512, 0, stream>>>(bout, jlist, Wl0, Wl1, sc, (float*)d_out);
}

// Round 6
// 148.557 us; speedup vs baseline: 5.8337x; 1.6164x over previous
//
#include <hip/hip_runtime.h>

#define N_NODES 4096
#define C_CH    128
#define E_ELEM  10
#define NP      4736          // padded sorted-node space (64-aligned per element)
#define TT      219           // 9 deg1 + 45 deg2 + 165 deg3 monomials
#define PSTRIDE (TT * 4)      // 876 floats per (e,c): [t][m], m0=L0, m1..3=L1
#define MAXCHUNK 32
#define CHUNK_J  256          // j-slots per k_poly block (256 thr x 1 node)

// ws layout (bytes):
#define WS_HIST    0
#define WS_PSTART  64
#define WS_PCUR    128
#define WS_CHE     256
#define WS_CHJ     512
#define WS_CHEND   768
#define WS_JLIST   1024        // int[4736]
#define WS_ELEM    20480       // int[4096]
#define WS_RANK    36864       // int[4096]
#define WS_S31     53248       // float[3465]
#define WS_S30     67136       // float[825]
#define WS_S21     70464       // float[405]
#define WS_S20     72128       // float[90]
#define WS_P       72704       // float[1280*876] = 4485120 B
#define WS_BOUT    4557824     // float[512*4736] = 9699328 B
#define WS_XS      14257152    // float[128*4736*9] = 21823488 B (optional)
#define WS_XS_END  36080640ull

__global__ void k_elem_hist(const float* __restrict__ attrs, int* __restrict__ elem,
                            int* __restrict__ hist, int* __restrict__ jlist) {
    int n = blockIdx.x * blockDim.x + threadIdx.x;
    if (n < NP) jlist[n] = -1;            // pad fill (runs before k_scatter)
    if (n >= N_NODES) return;
    const float* a = attrs + n * E_ELEM;
    float best = a[0];
    int e = 0;
#pragma unroll
    for (int k = 1; k < E_ELEM; ++k) {
        float v = a[k];
        if (v > best) { best = v; e = k; }
    }
    elem[n] = e;
    atomicAdd(&hist[e], 1);
}

__global__ void k_prefix(const int* __restrict__ hist, int* __restrict__ pstart,
                         int* __restrict__ pcursor, int* __restrict__ chE,
                         int* __restrict__ chJ, int* __restrict__ chEnd) {
    if (threadIdx.x != 0) return;
    int s = 0;
    for (int e = 0; e < E_ELEM; ++e) {
        pstart[e] = s;
        pcursor[e] = s;
        int plen = ((hist[e] + 63) >> 6) << 6;   // 64-align each element range
        s += plen;
    }
    pstart[E_ELEM] = s;
    int ci = 0;
    for (int e = 0; e < E_ELEM; ++e) {
        int base = pstart[e], end = pstart[e + 1];
        for (int ofs = base; ofs < end; ofs += CHUNK_J) {
            chE[ci] = e;
            chJ[ci] = ofs;
            chEnd[ci] = end;
            ++ci;
        }
    }
    for (; ci < MAXCHUNK; ++ci) chE[ci] = -1;
}

__global__ void k_scatter(const int* __restrict__ elem, int* __restrict__ pcursor,
                          int* __restrict__ jlist, int* __restrict__ rank) {
    int n = blockIdx.x * blockDim.x + threadIdx.x;
    if (n >= N_NODES) return;
    int e = elem[n];
    int pos = atomicAdd(&pcursor[e], 1);
    jlist[pos] = n;
    rank[n] = pos;
}

// Transpose x[n][c][i] -> xs[c][j][i] (sorted-j space). Reads fully coalesced.
__global__ void k_xpose(const float* __restrict__ x, const int* __restrict__ rank,
                        float* __restrict__ xs) {
    int tid = blockIdx.x * blockDim.x + threadIdx.x;
    if (tid >= N_NODES * C_CH * 9) return;
    int n = tid / (C_CH * 9);
    int q = tid - n * (C_CH * 9);
    int c = q / 9;
    int i = q - c * 9;
    xs[((size_t)c * NP + rank[n]) * 9 + i] = x[tid];
}

__device__ __forceinline__ void t3_decode(int t, int& a, int& b, int& i) {
    int cnt = 0;
    for (int aa = 0; aa < 9; ++aa)
        for (int bb = aa; bb < 9; ++bb) {
            int len = 9 - bb;
            if (t < cnt + len) { a = aa; b = bb; i = bb + (t - cnt); return; }
            cnt += len;
        }
    a = b = i = 8;
}

__device__ __forceinline__ void t2_decode(int t, int& a, int& b) {
    int cnt = 0;
    for (int aa = 0; aa < 9; ++aa) {
        int len = 9 - aa;
        if (t < cnt + len) { a = aa; b = aa + (t - cnt); return; }
        cnt += len;
    }
    a = b = 8;
}

// Symmetrize U tensors over monomial multisets — parallel, 4785 work items.
__global__ void k_sym(const float* __restrict__ U3_1, const float* __restrict__ U3_0,
                      const float* __restrict__ U2_1, const float* __restrict__ U2_0,
                      float* __restrict__ S31, float* __restrict__ S30,
                      float* __restrict__ S21, float* __restrict__ S20) {
    int q = blockIdx.x * blockDim.x + threadIdx.x;
    if (q < 3465) {                                 // S31 [m][t][p], p=7
        int m = q / 1155, r = q % 1155, t = r / 7, p = r % 7;
        int a, b, i;
        t3_decode(t, a, b, i);
#define U31(X, Y, Z) U3_1[((((m * 9 + (X)) * 9 + (Y)) * 9 + (Z)) * 7) + p]
        float s = U31(a, b, i);
        if (a == b && b == i) {}
        else if (a == b) s += U31(a, i, a) + U31(i, a, a);
        else if (b == i) s += U31(b, a, b) + U31(b, b, a);
        else s += U31(a, i, b) + U31(b, a, i) + U31(b, i, a) + U31(i, a, b) + U31(i, b, a);
#undef U31
        S31[q] = s;
        return;
    }
    q -= 3465;
    if (q < 825) {                                  // S30 [t][p], p=5
        int t = q / 5, p = q % 5;
        int a, b, i;
        t3_decode(t, a, b, i);
#define U30(X, Y, Z) U3_0[((((X) * 9 + (Y)) * 9 + (Z)) * 5) + p]
        float s = U30(a, b, i);
        if (a == b && b == i) {}
        else if (a == b) s += U30(a, i, a) + U30(i, a, a);
        else if (b == i) s += U30(b, a, b) + U30(b, b, a);
        else s += U30(a, i, b) + U30(b, a, i) + U30(b, i, a) + U30(i, a, b) + U30(i, b, a);
#undef U30
        S30[q] = s;
        return;
    }
    q -= 825;
    if (q < 405) {                                  // S21 [m][t][p], p=3
        int m = q / 135, r = q % 135, t = r / 3, p = r % 3;
        int a, b;
        t2_decode(t, a, b);
        float s = U2_1[(((m * 9 + a) * 9 + b) * 3) + p];
        if (a != b) s += U2_1[(((m * 9 + b) * 9 + a) * 3) + p];
        S21[q] = s;
        return;
    }
    q -= 405;
    if (q < 90) {                                   // S20 [t][p], p=2
        int t = q / 2, p = q % 2;
        int a, b;
        t2_decode(t, a, b);
        float s = U2_0[((a * 9 + b) * 2) + p];
        if (a != b) s += U2_0[((b * 9 + a) * 2) + p];
        S20[q] = s;
    }
}

// Fold element weights into symmetrized basis: P[e*128+c][t][m]
__global__ __launch_bounds__(128) void k_fold(
    const float* __restrict__ S31, const float* __restrict__ S30,
    const float* __restrict__ S21, const float* __restrict__ S20,
    const float* __restrict__ U1_1, const float* __restrict__ U1_0,
    const float* __restrict__ W3_1, const float* __restrict__ W3_0,
    const float* __restrict__ W2_1, const float* __restrict__ W2_0,
    const float* __restrict__ W1_1, const float* __restrict__ W1_0,
    float* __restrict__ P) {
    int e = blockIdx.x >> 7;
    int c = blockIdx.x & 127;
    float* Pout = P + (size_t)blockIdx.x * PSTRIDE;
    for (int q = threadIdx.x; q < PSTRIDE; q += 128) {
        int t = q >> 2, m = q & 3;
        float v;
        if (t < 9) {
            int a = t;
            v = (m == 0) ? U1_0[a] * W1_0[e * C_CH + c]
                         : U1_1[(m - 1) * 9 + a] * W1_1[e * C_CH + c];
        } else if (t < 54) {
            int t2 = t - 9;
            float s = 0.f;
            if (m == 0) {
#pragma unroll
                for (int p = 0; p < 2; ++p)
                    s = fmaf(S20[t2 * 2 + p], W2_0[(e * 2 + p) * C_CH + c], s);
            } else {
#pragma unroll
                for (int p = 0; p < 3; ++p)
                    s = fmaf(S21[((m - 1) * 45 + t2) * 3 + p], W2_1[(e * 3 + p) * C_CH + c], s);
            }
            v = s;
        } else {
            int t3 = t - 54;
            float s = 0.f;
            if (m == 0) {
#pragma unroll
                for (int p = 0; p < 5; ++p)
                    s = fmaf(S30[t3 * 5 + p], W3_0[(e * 5 + p) * C_CH + c], s);
            } else {
#pragma unroll
                for (int p = 0; p < 7; ++p)
                    s = fmaf(S31[((m - 1) * 165 + t3) * 7 + p], W3_1[(e * 7 + p) * C_CH + c], s);
            }
            v = s;
        }
        Pout[q] = v;
    }
}

// 219-monomial cubic, ONE node-channel per thread. Live set ~60 VGPR -> fits
// the RA's 64-VGPR/8-wave target with zero spill. sched_barrier(0) per (a,b)
// group keeps <=10 float4 LDS loads in flight.
__device__ __forceinline__ void poly_eval1(const float* __restrict__ sP,
                                           const float (&xv)[9], float (&acc)[4]) {
    const float* p1 = sP;
    const float* p2 = sP + 9 * 4;
    const float* p3 = sP + 54 * 4;
    int i2 = 0, i3 = 0;
#pragma unroll
    for (int a = 0; a < 9; ++a) {
        float4 q1 = *(const float4*)(p1 + a * 4);
        float xa = xv[a];
        acc[0] = fmaf(q1.x, xa, acc[0]);
        acc[1] = fmaf(q1.y, xa, acc[1]);
        acc[2] = fmaf(q1.z, xa, acc[2]);
        acc[3] = fmaf(q1.w, xa, acc[3]);
        __builtin_amdgcn_sched_barrier(0);
#pragma unroll
        for (int b = a; b < 9; ++b) {
            float4 q2 = *(const float4*)(p2 + i2 * 4);
            ++i2;
            float m2 = xv[a] * xv[b];
            acc[0] = fmaf(q2.x, m2, acc[0]);
            acc[1] = fmaf(q2.y, m2, acc[1]);
            acc[2] = fmaf(q2.z, m2, acc[2]);
            acc[3] = fmaf(q2.w, m2, acc[3]);
#pragma unroll
            for (int i = b; i < 9; ++i) {
                float4 q3 = *(const float4*)(p3 + i3 * 4);
                ++i3;
                float m3 = m2 * xv[i];
                acc[0] = fmaf(q3.x, m3, acc[0]);
                acc[1] = fmaf(q3.y, m3, acc[1]);
                acc[2] = fmaf(q3.z, m3, acc[2]);
                acc[3] = fmaf(q3.w, m3, acc[3]);
            }
            __builtin_amdgcn_sched_barrier(0);
        }
    }
}

template <bool XS>
__global__ __launch_bounds__(256) void k_poly(
    const float* __restrict__ xsrc, const int* __restrict__ jlist,
    const int* __restrict__ chE, const int* __restrict__ chJ,
    const int* __restrict__ chEnd, const float* __restrict__ P,
    float* __restrict__ bout) {
    int ci = blockIdx.y;
    int e = chE[ci];
    if (e < 0) return;
    e = __builtin_amdgcn_readfirstlane(e);
    int c = blockIdx.x;
    __shared__ __align__(16) float sP[PSTRIDE];
    const float* Pg = P + (size_t)(e * C_CH + c) * PSTRIDE;
    for (int t = threadIdx.x; t < PSTRIDE; t += 256) sP[t] = Pg[t];
    __syncthreads();

    const int end = chEnd[ci];
    const int j = chJ[ci] + threadIdx.x;
    if (j >= end) return;

    float xv[9];
    bool valid = true;
    if (XS) {
        const float* px = xsrc + ((size_t)c * NP + j) * 9;
#pragma unroll
        for (int i = 0; i < 9; ++i) xv[i] = px[i];
    } else {
        int n = jlist[j];
        valid = n >= 0;
        const float* px = xsrc + (size_t)((valid ? n : 0) * C_CH + c) * 9;
#pragma unroll
        for (int i = 0; i < 9; ++i) xv[i] = px[i];
    }
    float acc[4] = {};
    poly_eval1(sP, xv, acc);
    if (valid) {
#pragma unroll
        for (int m = 0; m < 4; ++m) bout[(size_t)(c * 4 + m) * NP + j] = acc[m];
    }
}

// j-lane GEMM: grid (NP/64, 16). y -> (slot s = y>>2, d-group dg = y&3).
// 256 thr: lane jj = tid&63 (j offset -> coalesced bout reads), wave wv =
// tid>>6 owns 8 cols dbase = dg*32 + wv*8 (wave-uniform -> Wl via SGPR loads).
// Per thread: 128 independent coalesced loads x 8 FMA each, acc[8] chains.
// (Round-5 version: 296 blocks, MLP~1 serialized L2 broadcast loads, 157 us.)
__global__ __launch_bounds__(256) void k_linear(
    const float* __restrict__ bout, const int* __restrict__ jlist,
    const float* __restrict__ Wl0, const float* __restrict__ Wl1,
    const float* __restrict__ sc, float* __restrict__ out) {
    const int s  = blockIdx.y >> 2;
    const int dg = blockIdx.y & 3;
    const int jj = threadIdx.x & 63;
    const int wv = threadIdx.x >> 6;
    const int dbase = dg * 32 + wv * 8;
    const int j = blockIdx.x * 64 + jj;
    const float* __restrict__ Wl = (s == 0) ? Wl0 : Wl1;
    const float* __restrict__ brow = bout + (size_t)s * NP + j;

    float acc[8];
#pragma unroll
    for (int k = 0; k < 8; ++k) acc[k] = 0.f;

#pragma unroll 4
    for (int cc = 0; cc < C_CH; ++cc) {
        float bval = brow[(size_t)cc * 4 * NP];
        const float* wrow = Wl + cc * C_CH + dbase;
#pragma unroll
        for (int k = 0; k < 8; ++k) acc[k] = fmaf(bval, wrow[k], acc[k]);
    }

    const int n = jlist[j];
    if (n < 0) return;
    const float inv = 0.08838834764831845f;  // 1/sqrt(128)
#pragma unroll
    for (int k = 0; k < 8; ++k) {
        int d = dbase + k;
        int col = (s == 0) ? d : (128 + d * 3 + (s - 1));
        out[n * 512 + col] = fmaf(acc[k], inv, sc[n * 512 + col]);
    }
}

extern "C" void kernel_launch(void* const* d_in, const int* in_sizes, int n_in,
                              void* d_out, int out_size, void* d_ws, size_t ws_size,
                              hipStream_t stream) {
    const float* x     = (const float*)d_in[0];
    const float* sc    = (const float*)d_in[1];
    const float* attrs = (const float*)d_in[2];
    const float* U3_0 = (const float*)d_in[3];
    const float* U2_0 = (const float*)d_in[4];
    const float* U1_0 = (const float*)d_in[5];
    const float* W3_0 = (const float*)d_in[6];
    const float* W2_0 = (const float*)d_in[7];
    const float* W1_0 = (const float*)d_in[8];
    const float* Wl0  = (const float*)d_in[9];
    const float* U3_1 = (const float*)d_in[10];
    const float* U2_1 = (const float*)d_in[11];
    const float* U1_1 = (const float*)d_in[12];
    const float* W3_1 = (const float*)d_in[13];
    const float* W2_1 = (const float*)d_in[14];
    const float* W1_1 = (const float*)d_in[15];
    const float* Wl1  = (const float*)d_in[16];

    char* ws = (char*)d_ws;
    int* hist    = (int*)(ws + WS_HIST);
    int* pstart  = (int*)(ws + WS_PSTART);
    int* pcursor = (int*)(ws + WS_PCUR);
    int* chE     = (int*)(ws + WS_CHE);
    int* chJ     = (int*)(ws + WS_CHJ);
    int* chEnd   = (int*)(ws + WS_CHEND);
    int* jlist   = (int*)(ws + WS_JLIST);
    int* elem    = (int*)(ws + WS_ELEM);
    int* rank    = (int*)(ws + WS_RANK);
    float* S31   = (float*)(ws + WS_S31);
    float* S30   = (float*)(ws + WS_S30);
    float* S21   = (float*)(ws + WS_S21);
    float* S20   = (float*)(ws + WS_S20);
    float* P     = (float*)(ws + WS_P);
    float* bout  = (float*)(ws + WS_BOUT);
    float* xs    = (float*)(ws + WS_XS);
    const bool use_xs = (ws_size >= WS_XS_END);

    hipMemsetAsync(hist, 0, E_ELEM * sizeof(int), stream);
    k_elem_hist<<<(NP + 255) / 256, 256, 0, stream>>>(attrs, elem, hist, jlist);
    k_prefix<<<1, 64, 0, stream>>>(hist, pstart, pcursor, chE, chJ, chEnd);
    k_scatter<<<16, 256, 0, stream>>>(elem, pcursor, jlist, rank);
    k_sym<<<19, 256, 0, stream>>>(U3_1, U3_0, U2_1, U2_0, S31, S30, S21, S20);
    k_fold<<<1280, 128, 0, stream>>>(S31, S30, S21, S20, U1_1, U1_0,
                                     W3_1, W3_0, W2_1, W2_0, W1_1, W1_0, P);
    if (use_xs) {
        k_xpose<<<(N_NODES * C_CH * 9 + 255) / 256, 256, 0, stream>>>(x, rank, xs);
        k_poly<true><<<dim3(128, MAXCHUNK), 256, 0, stream>>>(xs, jlist, chE, chJ,
                                                              chEnd, P, bout);
    } else {
        k_poly<false><<<dim3(128, MAXCHUNK), 256, 0, stream>>>(x, jlist, chE, chJ,
                                                               chEnd, P, bout);
    }
    k_linear<<<dim3(NP / 64, 16), 256, 0, stream>>>(bout, jlist, Wl0, Wl1, sc,
                                                    (float*)d_out);
}

// Round 7
// 119.791 us; speedup vs baseline: 7.2345x; 1.2401x over previous
//
#include <hip/hip_runtime.h>

#define N_NODES 4096
#define C_CH    128
#define E_ELEM  10
#define NP      4736          // padded sorted-node space (64-aligned per element)
#define TT      219           // 9 deg1 + 45 deg2 + 165 deg3 monomials
#define PSTRIDE (TT * 4)      // 876 floats per (e,c): [t][m], m0=L0, m1..3=L1
#define MAXCHUNK 32
#define CHUNK_J  256          // j-slots per k_poly block (256 thr x 1 node)

// ws layout (bytes):
#define WS_HIST    0
#define WS_PSTART  64
#define WS_PCUR    128
#define WS_CHE     256
#define WS_CHJ     512
#define WS_CHEND   768
#define WS_JLIST   1024        // int[4736]
#define WS_ELEM    20480       // int[4096]
#define WS_RANK    36864       // int[4096]
#define WS_S31     53248       // float[3465]
#define WS_S30     67136       // float[825]
#define WS_S21     70464       // float[405]
#define WS_S20     72128       // float[90]
#define WS_P       72704       // float[1280*876] = 4485120 B
#define WS_BOUT    4557824     // float[512*4736] = 9699328 B
#define WS_XS      14257152    // float[128*4736*9] = 21823488 B (optional)
#define WS_XS_END  36080640ull

__global__ void k_elem_hist(const float* __restrict__ attrs, int* __restrict__ elem,
                            int* __restrict__ hist, int* __restrict__ jlist) {
    int n = blockIdx.x * blockDim.x + threadIdx.x;
    if (n < NP) jlist[n] = -1;            // pad fill (runs before k_scatter)
    if (n >= N_NODES) return;
    const float* a = attrs + n * E_ELEM;
    float best = a[0];
    int e = 0;
#pragma unroll
    for (int k = 1; k < E_ELEM; ++k) {
        float v = a[k];
        if (v > best) { best = v; e = k; }
    }
    elem[n] = e;
    atomicAdd(&hist[e], 1);
}

__global__ void k_prefix(const int* __restrict__ hist, int* __restrict__ pstart,
                         int* __restrict__ pcursor, int* __restrict__ chE,
                         int* __restrict__ chJ, int* __restrict__ chEnd) {
    if (threadIdx.x != 0) return;
    int s = 0;
    for (int e = 0; e < E_ELEM; ++e) {
        pstart[e] = s;
        pcursor[e] = s;
        int plen = ((hist[e] + 63) >> 6) << 6;   // 64-align each element range
        s += plen;
    }
    pstart[E_ELEM] = s;
    int ci = 0;
    for (int e = 0; e < E_ELEM; ++e) {
        int base = pstart[e], end = pstart[e + 1];
        for (int ofs = base; ofs < end; ofs += CHUNK_J) {
            chE[ci] = e;
            chJ[ci] = ofs;
            chEnd[ci] = end;
            ++ci;
        }
    }
    for (; ci < MAXCHUNK; ++ci) chE[ci] = -1;
}

__global__ void k_scatter(const int* __restrict__ elem, int* __restrict__ pcursor,
                          int* __restrict__ jlist, int* __restrict__ rank) {
    int n = blockIdx.x * blockDim.x + threadIdx.x;
    if (n >= N_NODES) return;
    int e = elem[n];
    int pos = atomicAdd(&pcursor[e], 1);
    jlist[pos] = n;
    rank[n] = pos;
}

// Transpose x[n][c][i] -> xs[c][j][i] (sorted-j space). Reads fully coalesced.
__global__ void k_xpose(const float* __restrict__ x, const int* __restrict__ rank,
                        float* __restrict__ xs) {
    int tid = blockIdx.x * blockDim.x + threadIdx.x;
    if (tid >= N_NODES * C_CH * 9) return;
    int n = tid / (C_CH * 9);
    int q = tid - n * (C_CH * 9);
    int c = q / 9;
    int i = q - c * 9;
    xs[((size_t)c * NP + rank[n]) * 9 + i] = x[tid];
}

__device__ __forceinline__ void t3_decode(int t, int& a, int& b, int& i) {
    int cnt = 0;
    for (int aa = 0; aa < 9; ++aa)
        for (int bb = aa; bb < 9; ++bb) {
            int len = 9 - bb;
            if (t < cnt + len) { a = aa; b = bb; i = bb + (t - cnt); return; }
            cnt += len;
        }
    a = b = i = 8;
}

__device__ __forceinline__ void t2_decode(int t, int& a, int& b) {
    int cnt = 0;
    for (int aa = 0; aa < 9; ++aa) {
        int len = 9 - aa;
        if (t < cnt + len) { a = aa; b = aa + (t - cnt); return; }
        cnt += len;
    }
    a = b = 8;
}

// Symmetrize U tensors over monomial multisets — parallel, 4785 work items.
__global__ void k_sym(const float* __restrict__ U3_1, const float* __restrict__ U3_0,
                      const float* __restrict__ U2_1, const float* __restrict__ U2_0,
                      float* __restrict__ S31, float* __restrict__ S30,
                      float* __restrict__ S21, float* __restrict__ S20) {
    int q = blockIdx.x * blockDim.x + threadIdx.x;
    if (q < 3465) {                                 // S31 [m][t][p], p=7
        int m = q / 1155, r = q % 1155, t = r / 7, p = r % 7;
        int a, b, i;
        t3_decode(t, a, b, i);
#define U31(X, Y, Z) U3_1[((((m * 9 + (X)) * 9 + (Y)) * 9 + (Z)) * 7) + p]
        float s = U31(a, b, i);
        if (a == b && b == i) {}
        else if (a == b) s += U31(a, i, a) + U31(i, a, a);
        else if (b == i) s += U31(b, a, b) + U31(b, b, a);
        else s += U31(a, i, b) + U31(b, a, i) + U31(b, i, a) + U31(i, a, b) + U31(i, b, a);
#undef U31
        S31[q] = s;
        return;
    }
    q -= 3465;
    if (q < 825) {                                  // S30 [t][p], p=5
        int t = q / 5, p = q % 5;
        int a, b, i;
        t3_decode(t, a, b, i);
#define U30(X, Y, Z) U3_0[((((X) * 9 + (Y)) * 9 + (Z)) * 5) + p]
        float s = U30(a, b, i);
        if (a == b && b == i) {}
        else if (a == b) s += U30(a, i, a) + U30(i, a, a);
        else if (b == i) s += U30(b, a, b) + U30(b, b, a);
        else s += U30(a, i, b) + U30(b, a, i) + U30(b, i, a) + U30(i, a, b) + U30(i, b, a);
#undef U30
        S30[q] = s;
        return;
    }
    q -= 825;
    if (q < 405) {                                  // S21 [m][t][p], p=3
        int m = q / 135, r = q % 135, t = r / 3, p = r % 3;
        int a, b;
        t2_decode(t, a, b);
        float s = U2_1[(((m * 9 + a) * 9 + b) * 3) + p];
        if (a != b) s += U2_1[(((m * 9 + b) * 9 + a) * 3) + p];
        S21[q] = s;
        return;
    }
    q -= 405;
    if (q < 90) {                                   // S20 [t][p], p=2
        int t = q / 2, p = q % 2;
        int a, b;
        t2_decode(t, a, b);
        float s = U2_0[((a * 9 + b) * 2) + p];
        if (a != b) s += U2_0[((b * 9 + a) * 2) + p];
        S20[q] = s;
    }
}

// Fold element weights into symmetrized basis: P[e*128+c][t][m]
__global__ __launch_bounds__(128) void k_fold(
    const float* __restrict__ S31, const float* __restrict__ S30,
    const float* __restrict__ S21, const float* __restrict__ S20,
    const float* __restrict__ U1_1, const float* __restrict__ U1_0,
    const float* __restrict__ W3_1, const float* __restrict__ W3_0,
    const float* __restrict__ W2_1, const float* __restrict__ W2_0,
    const float* __restrict__ W1_1, const float* __restrict__ W1_0,
    float* __restrict__ P) {
    int e = blockIdx.x >> 7;
    int c = blockIdx.x & 127;
    float* Pout = P + (size_t)blockIdx.x * PSTRIDE;
    for (int q = threadIdx.x; q < PSTRIDE; q += 128) {
        int t = q >> 2, m = q & 3;
        float v;
        if (t < 9) {
            int a = t;
            v = (m == 0) ? U1_0[a] * W1_0[e * C_CH + c]
                         : U1_1[(m - 1) * 9 + a] * W1_1[e * C_CH + c];
        } else if (t < 54) {
            int t2 = t - 9;
            float s = 0.f;
            if (m == 0) {
#pragma unroll
                for (int p = 0; p < 2; ++p)
                    s = fmaf(S20[t2 * 2 + p], W2_0[(e * 2 + p) * C_CH + c], s);
            } else {
#pragma unroll
                for (int p = 0; p < 3; ++p)
                    s = fmaf(S21[((m - 1) * 45 + t2) * 3 + p], W2_1[(e * 3 + p) * C_CH + c], s);
            }
            v = s;
        } else {
            int t3 = t - 54;
            float s = 0.f;
            if (m == 0) {
#pragma unroll
                for (int p = 0; p < 5; ++p)
                    s = fmaf(S30[t3 * 5 + p], W3_0[(e * 5 + p) * C_CH + c], s);
            } else {
#pragma unroll
                for (int p = 0; p < 7; ++p)
                    s = fmaf(S31[((m - 1) * 165 + t3) * 7 + p], W3_1[(e * 7 + p) * C_CH + c], s);
            }
            v = s;
        }
        Pout[q] = v;
    }
}

// 219-monomial cubic, ONE node-channel per thread. Live set ~60 VGPR -> fits
// the RA's 64-VGPR/8-wave target with zero spill. sched_barrier(0) per (a,b)
// group keeps <=10 float4 LDS loads in flight.
__device__ __forceinline__ void poly_eval1(const float* __restrict__ sP,
                                           const float (&xv)[9], float (&acc)[4]) {
    const float* p1 = sP;
    const float* p2 = sP + 9 * 4;
    const float* p3 = sP + 54 * 4;
    int i2 = 0, i3 = 0;
#pragma unroll
    for (int a = 0; a < 9; ++a) {
        float4 q1 = *(const float4*)(p1 + a * 4);
        float xa = xv[a];
        acc[0] = fmaf(q1.x, xa, acc[0]);
        acc[1] = fmaf(q1.y, xa, acc[1]);
        acc[2] = fmaf(q1.z, xa, acc[2]);
        acc[3] = fmaf(q1.w, xa, acc[3]);
        __builtin_amdgcn_sched_barrier(0);
#pragma unroll
        for (int b = a; b < 9; ++b) {
            float4 q2 = *(const float4*)(p2 + i2 * 4);
            ++i2;
            float m2 = xv[a] * xv[b];
            acc[0] = fmaf(q2.x, m2, acc[0]);
            acc[1] = fmaf(q2.y, m2, acc[1]);
            acc[2] = fmaf(q2.z, m2, acc[2]);
            acc[3] = fmaf(q2.w, m2, acc[3]);
#pragma unroll
            for (int i = b; i < 9; ++i) {
                float4 q3 = *(const float4*)(p3 + i3 * 4);
                ++i3;
                float m3 = m2 * xv[i];
                acc[0] = fmaf(q3.x, m3, acc[0]);
                acc[1] = fmaf(q3.y, m3, acc[1]);
                acc[2] = fmaf(q3.z, m3, acc[2]);
                acc[3] = fmaf(q3.w, m3, acc[3]);
            }
            __builtin_amdgcn_sched_barrier(0);
        }
    }
}

template <bool XS>
__global__ __launch_bounds__(256) void k_poly(
    const float* __restrict__ xsrc, const int* __restrict__ jlist,
    const int* __restrict__ chE, const int* __restrict__ chJ,
    const int* __restrict__ chEnd, const float* __restrict__ P,
    float* __restrict__ bout) {
    int ci = blockIdx.y;
    int e = chE[ci];
    if (e < 0) return;
    e = __builtin_amdgcn_readfirstlane(e);
    int c = blockIdx.x;
    __shared__ __align__(16) float sP[PSTRIDE];
    const float* Pg = P + (size_t)(e * C_CH + c) * PSTRIDE;
    for (int t = threadIdx.x; t < PSTRIDE; t += 256) sP[t] = Pg[t];
    __syncthreads();

    const int end = chEnd[ci];
    const int j = chJ[ci] + threadIdx.x;
    if (j >= end) return;

    float xv[9];
    bool valid = true;
    if (XS) {
        const float* px = xsrc + ((size_t)c * NP + j) * 9;
#pragma unroll
        for (int i = 0; i < 9; ++i) xv[i] = px[i];
    } else {
        int n = jlist[j];
        valid = n >= 0;
        const float* px = xsrc + (size_t)((valid ? n : 0) * C_CH + c) * 9;
#pragma unroll
        for (int i = 0; i < 9; ++i) xv[i] = px[i];
    }
    float acc[4] = {};
    poly_eval1(sP, xv, acc);
    if (valid) {
#pragma unroll
        for (int m = 0; m < 4; ++m) bout[(size_t)(c * 4 + m) * NP + j] = acc[m];
    }
}

// j-lane GEMM v3. R6 miss: Wl reads were VECTOR broadcast loads (compiler
// can't prove wv-derived dbase wave-uniform) -> 9 vec-loads per 8 FMA,
// latency-bound at VALUBusy 9%. Fix: readfirstlane(dbase) makes the W
// address provably scalar -> s_load via constant cache (off the VMEM pipe);
// bval loads batched 16-deep into registers (outer loop dynamic so nothing
// hoists) -> 8 latency rounds of 16 in-flight loads + 128 FMA each.
__global__ __launch_bounds__(256) void k_linear(
    const float* __restrict__ bout, const int* __restrict__ jlist,
    const float* __restrict__ Wl0, const float* __restrict__ Wl1,
    const float* __restrict__ sc, float* __restrict__ out) {
    const int s  = blockIdx.y >> 2;
    const int dg = blockIdx.y & 3;
    const int jj = threadIdx.x & 63;
    const int wv = threadIdx.x >> 6;
    const int dbase = __builtin_amdgcn_readfirstlane(dg * 32 + wv * 8);
    const int j = blockIdx.x * 64 + jj;
    const float* __restrict__ Wl = (s == 0) ? Wl0 : Wl1;
    const float* __restrict__ brow = bout + (size_t)s * NP + j;

    float acc[8];
#pragma unroll
    for (int k = 0; k < 8; ++k) acc[k] = 0.f;

#pragma unroll 1
    for (int cc0 = 0; cc0 < C_CH; cc0 += 16) {
        float bv[16];
#pragma unroll
        for (int t = 0; t < 16; ++t)
            bv[t] = brow[(size_t)(cc0 + t) * 4 * NP];
#pragma unroll
        for (int t = 0; t < 16; ++t) {
            const float* wrow = Wl + (cc0 + t) * C_CH + dbase;  // scalar addr
#pragma unroll
            for (int k = 0; k < 8; ++k) acc[k] = fmaf(bv[t], wrow[k], acc[k]);
        }
    }

    const int n = jlist[j];
    if (n < 0) return;
    const float inv = 0.08838834764831845f;  // 1/sqrt(128)
#pragma unroll
    for (int k = 0; k < 8; ++k) {
        int d = dbase + k;
        int col = (s == 0) ? d : (128 + d * 3 + (s - 1));
        out[n * 512 + col] = fmaf(acc[k], inv, sc[n * 512 + col]);
    }
}

extern "C" void kernel_launch(void* const* d_in, const int* in_sizes, int n_in,
                              void* d_out, int out_size, void* d_ws, size_t ws_size,
                              hipStream_t stream) {
    const float* x     = (const float*)d_in[0];
    const float* sc    = (const float*)d_in[1];
    const float* attrs = (const float*)d_in[2];
    const float* U3_0 = (const float*)d_in[3];
    const float* U2_0 = (const float*)d_in[4];
    const float* U1_0 = (const float*)d_in[5];
    const float* W3_0 = (const float*)d_in[6];
    const float* W2_0 = (const float*)d_in[7];
    const float* W1_0 = (const float*)d_in[8];
    const float* Wl0  = (const float*)d_in[9];
    const float* U3_1 = (const float*)d_in[10];
    const float* U2_1 = (const float*)d_in[11];
    const float* U1_1 = (const float*)d_in[12];
    const float* W3_1 = (const float*)d_in[13];
    const float* W2_1 = (const float*)d_in[14];
    const float* W1_1 = (const float*)d_in[15];
    const float* Wl1  = (const float*)d_in[16];

    char* ws = (char*)d_ws;
    int* hist    = (int*)(ws + WS_HIST);
    int* pstart  = (int*)(ws + WS_PSTART);
    int* pcursor = (int*)(ws + WS_PCUR);
    int* chE     = (int*)(ws + WS_CHE);
    int* chJ     = (int*)(ws + WS_CHJ);
    int* chEnd   = (int*)(ws + WS_CHEND);
    int* jlist   = (int*)(ws + WS_JLIST);
    int* elem    = (int*)(ws + WS_ELEM);
    int* rank    = (int*)(ws + WS_RANK);
    float* S31   = (float*)(ws + WS_S31);
    float* S30   = (float*)(ws + WS_S30);
    float* S21   = (float*)(ws + WS_S21);
    float* S20   = (float*)(ws + WS_S20);
    float* P     = (float*)(ws + WS_P);
    float* bout  = (float*)(ws + WS_BOUT);
    float* xs    = (float*)(ws + WS_XS);
    const bool use_xs = (ws_size >= WS_XS_END);

    hipMemsetAsync(hist, 0, E_ELEM * sizeof(int), stream);
    k_elem_hist<<<(NP + 255) / 256, 256, 0, stream>>>(attrs, elem, hist, jlist);
    k_prefix<<<1, 64, 0, stream>>>(hist, pstart, pcursor, chE, chJ, chEnd);
    k_scatter<<<16, 256, 0, stream>>>(elem, pcursor, jlist, rank);
    k_sym<<<19, 256, 0, stream>>>(U3_1, U3_0, U2_1, U2_0, S31, S30, S21, S20);
    k_fold<<<1280, 128, 0, stream>>>(S31, S30, S21, S20, U1_1, U1_0,
                                     W3_1, W3_0, W2_1, W2_0, W1_1, W1_0, P);
    if (use_xs) {
        k_xpose<<<(N_NODES * C_CH * 9 + 255) / 256, 256, 0, stream>>>(x, rank, xs);
        k_poly<true><<<dim3(128, MAXCHUNK), 256, 0, stream>>>(xs, jlist, chE, chJ,
                                                              chEnd, P, bout);
    } else {
        k_poly<false><<<dim3(128, MAXCHUNK), 256, 0, stream>>>(x, jlist, chE, chJ,
                                                               chEnd, P, bout);
    }
    k_linear<<<dim3(NP / 64, 16), 256, 0, stream>>>(bout, jlist, Wl0, Wl1, sc,
                                                    (float*)d_out);
}

// Round 8
// 113.649 us; speedup vs baseline: 7.6255x; 1.0540x over previous
//
#include <hip/hip_runtime.h>

#define N_NODES 4096
#define C_CH    128
#define E_ELEM  10
#define NP      4736          // padded sorted-node space (64-aligned per element)
#define TT      219           // 9 deg1 + 45 deg2 + 165 deg3 monomials
#define PSTRIDE (TT * 4)      // 876 floats per (e,c): [t][m], m0=L0, m1..3=L1
#define MAXCHUNK 32
#define CHUNK_J  256          // j-slots per k_poly block (256 thr x 1 node)

// ws layout (bytes):
#define WS_PSTART  64
#define WS_PCUR    128
#define WS_CHE     256
#define WS_CHJ     512
#define WS_CHEND   768
#define WS_JLIST   1024        // int[4736]
#define WS_ELEM    20480       // int[4096]
#define WS_RANK    36864       // int[4096]
#define WS_S31     53248       // float[3465]
#define WS_S30     67136       // float[825]
#define WS_S21     70464       // float[405]
#define WS_S20     72128       // float[90]
#define WS_P       72704       // float[1280*876] = 4485120 B
#define WS_BOUT    4557824     // float[512*4736] = 9699328 B
#define WS_XS      14257152    // float[128*4736*9] = 21823488 B (optional)
#define WS_XS_END  36080640ull

// elem decode + jlist pad fill (no global hist: k_prefix histograms elem[]
// itself -> removes the hipMemsetAsync fill kernel from the timed graph,
// which profiled at ~43 us/call in R7).
__global__ void k_elem(const float* __restrict__ attrs, int* __restrict__ elem,
                       int* __restrict__ jlist) {
    int n = blockIdx.x * blockDim.x + threadIdx.x;
    if (n < NP) jlist[n] = -1;            // pad fill (runs before k_scatter)
    if (n >= N_NODES) return;
    const float* a = attrs + n * E_ELEM;
    float best = a[0];
    int e = 0;
#pragma unroll
    for (int k = 1; k < E_ELEM; ++k) {
        float v = a[k];
        if (v > best) { best = v; e = k; }
    }
    elem[n] = e;
}

__global__ void k_prefix(const int* __restrict__ elem, int* __restrict__ pstart,
                         int* __restrict__ pcursor, int* __restrict__ chE,
                         int* __restrict__ chJ, int* __restrict__ chEnd) {
    __shared__ int h[E_ELEM];
    int tid = threadIdx.x;
    if (tid < E_ELEM) h[tid] = 0;
    __syncthreads();
    for (int n = tid; n < N_NODES; n += 256) atomicAdd(&h[elem[n]], 1);
    __syncthreads();
    if (tid != 0) return;
    int s = 0;
    for (int e = 0; e < E_ELEM; ++e) {
        pstart[e] = s;
        pcursor[e] = s;
        int plen = ((h[e] + 63) >> 6) << 6;      // 64-align each element range
        s += plen;
    }
    pstart[E_ELEM] = s;
    int ci = 0;
    for (int e = 0; e < E_ELEM; ++e) {
        int base = pstart[e], end = pstart[e + 1];
        for (int ofs = base; ofs < end; ofs += CHUNK_J) {
            chE[ci] = e;
            chJ[ci] = ofs;
            chEnd[ci] = end;
            ++ci;
        }
    }
    for (; ci < MAXCHUNK; ++ci) chE[ci] = -1;
}

__global__ void k_scatter(const int* __restrict__ elem, int* __restrict__ pcursor,
                          int* __restrict__ jlist, int* __restrict__ rank) {
    int n = blockIdx.x * blockDim.x + threadIdx.x;
    if (n >= N_NODES) return;
    int e = elem[n];
    int pos = atomicAdd(&pcursor[e], 1);
    jlist[pos] = n;
    rank[n] = pos;
}

// Transpose x[n][c][i] -> xs[c][j][i] (sorted-j space). Reads fully coalesced.
__global__ void k_xpose(const float* __restrict__ x, const int* __restrict__ rank,
                        float* __restrict__ xs) {
    int tid = blockIdx.x * blockDim.x + threadIdx.x;
    if (tid >= N_NODES * C_CH * 9) return;
    int n = tid / (C_CH * 9);
    int q = tid - n * (C_CH * 9);
    int c = q / 9;
    int i = q - c * 9;
    xs[((size_t)c * NP + rank[n]) * 9 + i] = x[tid];
}

__device__ __forceinline__ void t3_decode(int t, int& a, int& b, int& i) {
    int cnt = 0;
    for (int aa = 0; aa < 9; ++aa)
        for (int bb = aa; bb < 9; ++bb) {
            int len = 9 - bb;
            if (t < cnt + len) { a = aa; b = bb; i = bb + (t - cnt); return; }
            cnt += len;
        }
    a = b = i = 8;
}

__device__ __forceinline__ void t2_decode(int t, int& a, int& b) {
    int cnt = 0;
    for (int aa = 0; aa < 9; ++aa) {
        int len = 9 - aa;
        if (t < cnt + len) { a = aa; b = aa + (t - cnt); return; }
        cnt += len;
    }
    a = b = 8;
}

// Symmetrize U tensors over monomial multisets — parallel, 4785 work items.
__global__ void k_sym(const float* __restrict__ U3_1, const float* __restrict__ U3_0,
                      const float* __restrict__ U2_1, const float* __restrict__ U2_0,
                      float* __restrict__ S31, float* __restrict__ S30,
                      float* __restrict__ S21, float* __restrict__ S20) {
    int q = blockIdx.x * blockDim.x + threadIdx.x;
    if (q < 3465) {                                 // S31 [m][t][p], p=7
        int m = q / 1155, r = q % 1155, t = r / 7, p = r % 7;
        int a, b, i;
        t3_decode(t, a, b, i);
#define U31(X, Y, Z) U3_1[((((m * 9 + (X)) * 9 + (Y)) * 9 + (Z)) * 7) + p]
        float s = U31(a, b, i);
        if (a == b && b == i) {}
        else if (a == b) s += U31(a, i, a) + U31(i, a, a);
        else if (b == i) s += U31(b, a, b) + U31(b, b, a);
        else s += U31(a, i, b) + U31(b, a, i) + U31(b, i, a) + U31(i, a, b) + U31(i, b, a);
#undef U31
        S31[q] = s;
        return;
    }
    q -= 3465;
    if (q < 825) {                                  // S30 [t][p], p=5
        int t = q / 5, p = q % 5;
        int a, b, i;
        t3_decode(t, a, b, i);
#define U30(X, Y, Z) U3_0[((((X) * 9 + (Y)) * 9 + (Z)) * 5) + p]
        float s = U30(a, b, i);
        if (a == b && b == i) {}
        else if (a == b) s += U30(a, i, a) + U30(i, a, a);
        else if (b == i) s += U30(b, a, b) + U30(b, b, a);
        else s += U30(a, i, b) + U30(b, a, i) + U30(b, i, a) + U30(i, a, b) + U30(i, b, a);
#undef U30
        S30[q] = s;
        return;
    }
    q -= 825;
    if (q < 405) {                                  // S21 [m][t][p], p=3
        int m = q / 135, r = q % 135, t = r / 3, p = r % 3;
        int a, b;
        t2_decode(t, a, b);
        float s = U2_1[(((m * 9 + a) * 9 + b) * 3) + p];
        if (a != b) s += U2_1[(((m * 9 + b) * 9 + a) * 3) + p];
        S21[q] = s;
        return;
    }
    q -= 405;
    if (q < 90) {                                   // S20 [t][p], p=2
        int t = q / 2, p = q % 2;
        int a, b;
        t2_decode(t, a, b);
        float s = U2_0[((a * 9 + b) * 2) + p];
        if (a != b) s += U2_0[((b * 9 + a) * 2) + p];
        S20[q] = s;
    }
}

// Fold element weights into symmetrized basis: P[e*128+c][t][m]
__global__ __launch_bounds__(128) void k_fold(
    const float* __restrict__ S31, const float* __restrict__ S30,
    const float* __restrict__ S21, const float* __restrict__ S20,
    const float* __restrict__ U1_1, const float* __restrict__ U1_0,
    const float* __restrict__ W3_1, const float* __restrict__ W3_0,
    const float* __restrict__ W2_1, const float* __restrict__ W2_0,
    const float* __restrict__ W1_1, const float* __restrict__ W1_0,
    float* __restrict__ P) {
    int e = blockIdx.x >> 7;
    int c = blockIdx.x & 127;
    float* Pout = P + (size_t)blockIdx.x * PSTRIDE;
    for (int q = threadIdx.x; q < PSTRIDE; q += 128) {
        int t = q >> 2, m = q & 3;
        float v;
        if (t < 9) {
            int a = t;
            v = (m == 0) ? U1_0[a] * W1_0[e * C_CH + c]
                         : U1_1[(m - 1) * 9 + a] * W1_1[e * C_CH + c];
        } else if (t < 54) {
            int t2 = t - 9;
            float s = 0.f;
            if (m == 0) {
#pragma unroll
                for (int p = 0; p < 2; ++p)
                    s = fmaf(S20[t2 * 2 + p], W2_0[(e * 2 + p) * C_CH + c], s);
            } else {
#pragma unroll
                for (int p = 0; p < 3; ++p)
                    s = fmaf(S21[((m - 1) * 45 + t2) * 3 + p], W2_1[(e * 3 + p) * C_CH + c], s);
            }
            v = s;
        } else {
            int t3 = t - 54;
            float s = 0.f;
            if (m == 0) {
#pragma unroll
                for (int p = 0; p < 5; ++p)
                    s = fmaf(S30[t3 * 5 + p], W3_0[(e * 5 + p) * C_CH + c], s);
            } else {
#pragma unroll
                for (int p = 0; p < 7; ++p)
                    s = fmaf(S31[((m - 1) * 165 + t3) * 7 + p], W3_1[(e * 7 + p) * C_CH + c], s);
            }
            v = s;
        }
        Pout[q] = v;
    }
}

// 219-monomial cubic. Coefficients read DIRECTLY from global P through a
// provably-uniform address (e readfirstlane'd, c=blockIdx.x, t unrolled-const,
// __restrict__ no-alias) -> compiler emits s_load through the constant cache;
// coefficients become SGPR operands of v_fma. This removes all DS traffic
// (R7: 4 waves x 219 ds_read_b128 per block oversubscribed the 4-SIMD-shared
// LDS pipe ~5x vs VALU). sched_barrier(0) per (a,b) group: <=10 float4 loads
// (40 SGPRs) in flight, no scalar spill.
__device__ __forceinline__ void poly_eval1(const float* __restrict__ sP,
                                           const float (&xv)[9], float (&acc)[4]) {
    const float* p1 = sP;
    const float* p2 = sP + 9 * 4;
    const float* p3 = sP + 54 * 4;
    int i2 = 0, i3 = 0;
#pragma unroll
    for (int a = 0; a < 9; ++a) {
        float4 q1 = *(const float4*)(p1 + a * 4);
        float xa = xv[a];
        acc[0] = fmaf(q1.x, xa, acc[0]);
        acc[1] = fmaf(q1.y, xa, acc[1]);
        acc[2] = fmaf(q1.z, xa, acc[2]);
        acc[3] = fmaf(q1.w, xa, acc[3]);
        __builtin_amdgcn_sched_barrier(0);
#pragma unroll
        for (int b = a; b < 9; ++b) {
            float4 q2 = *(const float4*)(p2 + i2 * 4);
            ++i2;
            float m2 = xv[a] * xv[b];
            acc[0] = fmaf(q2.x, m2, acc[0]);
            acc[1] = fmaf(q2.y, m2, acc[1]);
            acc[2] = fmaf(q2.z, m2, acc[2]);
            acc[3] = fmaf(q2.w, m2, acc[3]);
#pragma unroll
            for (int i = b; i < 9; ++i) {
                float4 q3 = *(const float4*)(p3 + i3 * 4);
                ++i3;
                float m3 = m2 * xv[i];
                acc[0] = fmaf(q3.x, m3, acc[0]);
                acc[1] = fmaf(q3.y, m3, acc[1]);
                acc[2] = fmaf(q3.z, m3, acc[2]);
                acc[3] = fmaf(q3.w, m3, acc[3]);
            }
            __builtin_amdgcn_sched_barrier(0);
        }
    }
}

template <bool XS>
__global__ __launch_bounds__(256) void k_poly(
    const float* __restrict__ xsrc, const int* __restrict__ jlist,
    const int* __restrict__ chE, const int* __restrict__ chJ,
    const int* __restrict__ chEnd, const float* __restrict__ P,
    float* __restrict__ bout) {
    int ci = blockIdx.y;
    int e = chE[ci];
    if (e < 0) return;
    e = __builtin_amdgcn_readfirstlane(e);
    int c = blockIdx.x;
    const float* __restrict__ Pg = P + (size_t)(e * C_CH + c) * PSTRIDE;

    const int end = chEnd[ci];
    const int j = chJ[ci] + threadIdx.x;
    if (j >= end) return;

    float xv[9];
    bool valid = true;
    if (XS) {
        const float* px = xsrc + ((size_t)c * NP + j) * 9;
#pragma unroll
        for (int i = 0; i < 9; ++i) xv[i] = px[i];
    } else {
        int n = jlist[j];
        valid = n >= 0;
        const float* px = xsrc + (size_t)((valid ? n : 0) * C_CH + c) * 9;
#pragma unroll
        for (int i = 0; i < 9; ++i) xv[i] = px[i];
    }
    float acc[4] = {};
    poly_eval1(Pg, xv, acc);
    if (valid) {
#pragma unroll
        for (int m = 0; m < 4; ++m) bout[(size_t)(c * 4 + m) * NP + j] = acc[m];
    }
}

// j-lane GEMM: lane jj -> coalesced bout reads; readfirstlane(dbase) -> W
// reads are s_loads off the VMEM pipe; bval loads batched 16-deep.
__global__ __launch_bounds__(256) void k_linear(
    const float* __restrict__ bout, const int* __restrict__ jlist,
    const float* __restrict__ Wl0, const float* __restrict__ Wl1,
    const float* __restrict__ sc, float* __restrict__ out) {
    const int s  = blockIdx.y >> 2;
    const int dg = blockIdx.y & 3;
    const int jj = threadIdx.x & 63;
    const int wv = threadIdx.x >> 6;
    const int dbase = __builtin_amdgcn_readfirstlane(dg * 32 + wv * 8);
    const int j = blockIdx.x * 64 + jj;
    const float* __restrict__ Wl = (s == 0) ? Wl0 : Wl1;
    const float* __restrict__ brow = bout + (size_t)s * NP + j;

    float acc[8];
#pragma unroll
    for (int k = 0; k < 8; ++k) acc[k] = 0.f;

#pragma unroll 1
    for (int cc0 = 0; cc0 < C_CH; cc0 += 16) {
        float bv[16];
#pragma unroll
        for (int t = 0; t < 16; ++t)
            bv[t] = brow[(size_t)(cc0 + t) * 4 * NP];
#pragma unroll
        for (int t = 0; t < 16; ++t) {
            const float* wrow = Wl + (cc0 + t) * C_CH + dbase;  // scalar addr
#pragma unroll
            for (int k = 0; k < 8; ++k) acc[k] = fmaf(bv[t], wrow[k], acc[k]);
        }
    }

    const int n = jlist[j];
    if (n < 0) return;
    const float inv = 0.08838834764831845f;  // 1/sqrt(128)
#pragma unroll
    for (int k = 0; k < 8; ++k) {
        int d = dbase + k;
        int col = (s == 0) ? d : (128 + d * 3 + (s - 1));
        out[n * 512 + col] = fmaf(acc[k], inv, sc[n * 512 + col]);
    }
}

extern "C" void kernel_launch(void* const* d_in, const int* in_sizes, int n_in,
                              void* d_out, int out_size, void* d_ws, size_t ws_size,
                              hipStream_t stream) {
    const float* x     = (const float*)d_in[0];
    const float* sc    = (const float*)d_in[1];
    const float* attrs = (const float*)d_in[2];
    const float* U3_0 = (const float*)d_in[3];
    const float* U2_0 = (const float*)d_in[4];
    const float* U1_0 = (const float*)d_in[5];
    const float* W3_0 = (const float*)d_in[6];
    const float* W2_0 = (const float*)d_in[7];
    const float* W1_0 = (const float*)d_in[8];
    const float* Wl0  = (const float*)d_in[9];
    const float* U3_1 = (const float*)d_in[10];
    const float* U2_1 = (const float*)d_in[11];
    const float* U1_1 = (const float*)d_in[12];
    const float* W3_1 = (const float*)d_in[13];
    const float* W2_1 = (const float*)d_in[14];
    const float* W1_1 = (const float*)d_in[15];
    const float* Wl1  = (const float*)d_in[16];

    char* ws = (char*)d_ws;
    int* pstart  = (int*)(ws + WS_PSTART);
    int* pcursor = (int*)(ws + WS_PCUR);
    int* chE     = (int*)(ws + WS_CHE);
    int* chJ     = (int*)(ws + WS_CHJ);
    int* chEnd   = (int*)(ws + WS_CHEND);
    int* jlist   = (int*)(ws + WS_JLIST);
    int* elem    = (int*)(ws + WS_ELEM);
    int* rank    = (int*)(ws + WS_RANK);
    float* S31   = (float*)(ws + WS_S31);
    float* S30   = (float*)(ws + WS_S30);
    float* S21   = (float*)(ws + WS_S21);
    float* S20   = (float*)(ws + WS_S20);
    float* P     = (float*)(ws + WS_P);
    float* bout  = (float*)(ws + WS_BOUT);
    float* xs    = (float*)(ws + WS_XS);
    const bool use_xs = (ws_size >= WS_XS_END);

    k_elem<<<(NP + 255) / 256, 256, 0, stream>>>(attrs, elem, jlist);
    k_prefix<<<1, 256, 0, stream>>>(elem, pstart, pcursor, chE, chJ, chEnd);
    k_scatter<<<16, 256, 0, stream>>>(elem, pcursor, jlist, rank);
    k_sym<<<19, 256, 0, stream>>>(U3_1, U3_0, U2_1, U2_0, S31, S30, S21, S20);
    k_fold<<<1280, 128, 0, stream>>>(S31, S30, S21, S20, U1_1, U1_0,
                                     W3_1, W3_0, W2_1, W2_0, W1_1, W1_0, P);
    if (use_xs) {
        k_xpose<<<(N_NODES * C_CH * 9 + 255) / 256, 256, 0, stream>>>(x, rank, xs);
        k_poly<true><<<dim3(128, MAXCHUNK), 256, 0, stream>>>(xs, jlist, chE, chJ,
                                                              chEnd, P, bout);
    } else {
        k_poly<false><<<dim3(128, MAXCHUNK), 256, 0, stream>>>(x, jlist, chE, chJ,
                                                               chEnd, P, bout);
    }
    k_linear<<<dim3(NP / 64, 16), 256, 0, stream>>>(bout, jlist, Wl0, Wl1, sc,
                                                    (float*)d_out);
}

// Round 9
// 105.690 us; speedup vs baseline: 8.1997x; 1.0753x over previous
//
#include <hip/hip_runtime.h>

#define N_NODES 4096
#define C_CH    128
#define E_ELEM  10
#define NP      4736          // padded sorted-node space (64-aligned per element)
#define TT      219           // 9 deg1 + 45 deg2 + 165 deg3 monomials
#define PSTRIDE (TT * 4)      // 876 floats per (e,c): [t][m], m0=L0, m1..3=L1
#define MAXCHUNK 32
#define CHUNK_J  256          // j-slots per k_poly block (256 thr x 1 node)

// ws layout (bytes):
#define WS_CHE     256
#define WS_CHJ     512
#define WS_CHEND   768
#define WS_JLIST   1024        // int[4736]
#define WS_ELEM    20480       // int[4096]
#define WS_RANK    36864       // int[4096] (unused now, kept for layout)
#define WS_S31     53248       // float[3465]
#define WS_S30     67136       // float[825]
#define WS_S21     70464       // float[405]
#define WS_S20     72128       // float[90]
#define WS_P       72704       // float[1280*876] = 4485120 B
#define WS_BOUT    4557824     // float[512*4736] = 9699328 B
#define WS_XS      14257152    // float[128*4736*9] = 21823488 B
#define WS_XS_END  36080640ull

__device__ __forceinline__ void t3_decode(int t, int& a, int& b, int& i) {
    int cnt = 0;
    for (int aa = 0; aa < 9; ++aa)
        for (int bb = aa; bb < 9; ++bb) {
            int len = 9 - bb;
            if (t < cnt + len) { a = aa; b = bb; i = bb + (t - cnt); return; }
            cnt += len;
        }
    a = b = i = 8;
}

__device__ __forceinline__ void t2_decode(int t, int& a, int& b) {
    int cnt = 0;
    for (int aa = 0; aa < 9; ++aa) {
        int len = 9 - aa;
        if (t < cnt + len) { a = aa; b = aa + (t - cnt); return; }
        cnt += len;
    }
    a = b = 8;
}

// Fused front: blocks 0-18 symmetrize U (4785 items); blocks 19-34 decode
// elem (4096 nodes). Independent work sharing one dispatch (R8: 8 serialized
// launches with full-drain gaps were a measurable fraction of 113 us).
__global__ __launch_bounds__(256) void k_front(
    const float* __restrict__ attrs, int* __restrict__ elem,
    const float* __restrict__ U3_1, const float* __restrict__ U3_0,
    const float* __restrict__ U2_1, const float* __restrict__ U2_0,
    float* __restrict__ S31, float* __restrict__ S30,
    float* __restrict__ S21, float* __restrict__ S20) {
    int bid = blockIdx.x;
    if (bid >= 19) {
        int n = (bid - 19) * 256 + threadIdx.x;
        if (n >= N_NODES) return;
        const float* a = attrs + n * E_ELEM;
        float best = a[0];
        int e = 0;
#pragma unroll
        for (int k = 1; k < E_ELEM; ++k) {
            float v = a[k];
            if (v > best) { best = v; e = k; }
        }
        elem[n] = e;
        return;
    }
    int q = bid * 256 + threadIdx.x;
    if (q < 3465) {                                 // S31 [m][t][p], p=7
        int m = q / 1155, r = q % 1155, t = r / 7, p = r % 7;
        int a, b, i;
        t3_decode(t, a, b, i);
#define U31(X, Y, Z) U3_1[((((m * 9 + (X)) * 9 + (Y)) * 9 + (Z)) * 7) + p]
        float s = U31(a, b, i);
        if (a == b && b == i) {}
        else if (a == b) s += U31(a, i, a) + U31(i, a, a);
        else if (b == i) s += U31(b, a, b) + U31(b, b, a);
        else s += U31(a, i, b) + U31(b, a, i) + U31(b, i, a) + U31(i, a, b) + U31(i, b, a);
#undef U31
        S31[q] = s;
        return;
    }
    q -= 3465;
    if (q < 825) {                                  // S30 [t][p], p=5
        int t = q / 5, p = q % 5;
        int a, b, i;
        t3_decode(t, a, b, i);
#define U30(X, Y, Z) U3_0[((((X) * 9 + (Y)) * 9 + (Z)) * 5) + p]
        float s = U30(a, b, i);
        if (a == b && b == i) {}
        else if (a == b) s += U30(a, i, a) + U30(i, a, a);
        else if (b == i) s += U30(b, a, b) + U30(b, b, a);
        else s += U30(a, i, b) + U30(b, a, i) + U30(b, i, a) + U30(i, a, b) + U30(i, b, a);
#undef U30
        S30[q] = s;
        return;
    }
    q -= 825;
    if (q < 405) {                                  // S21 [m][t][p], p=3
        int m = q / 135, r = q % 135, t = r / 3, p = r % 3;
        int a, b;
        t2_decode(t, a, b);
        float s = U2_1[(((m * 9 + a) * 9 + b) * 3) + p];
        if (a != b) s += U2_1[(((m * 9 + b) * 9 + a) * 3) + p];
        S21[q] = s;
        return;
    }
    q -= 405;
    if (q < 90) {                                   // S20 [t][p], p=2
        int t = q / 2, p = q % 2;
        int a, b;
        t2_decode(t, a, b);
        float s = U2_0[((a * 9 + b) * 2) + p];
        if (a != b) s += U2_0[((b * 9 + a) * 2) + p];
        S20[q] = s;
    }
}

// Single-block sort: LDS histogram -> prefix -> chunk table -> jlist pad-fill
// -> LDS-cursor scatter. Replaces k_prefix + k_scatter (+ global atomics).
// Output value is dispatch-order independent: out[n] depends only on n.
__global__ __launch_bounds__(1024) void k_sort(
    const int* __restrict__ elem, int* __restrict__ jlist,
    int* __restrict__ chE, int* __restrict__ chJ, int* __restrict__ chEnd) {
    __shared__ int h[E_ELEM];
    __shared__ int cur[E_ELEM];
    int tid = threadIdx.x;
    if (tid < E_ELEM) h[tid] = 0;
    __syncthreads();
    for (int n = tid; n < N_NODES; n += 1024) atomicAdd(&h[elem[n]], 1);
    for (int p = tid; p < NP; p += 1024) jlist[p] = -1;
    __syncthreads();
    if (tid == 0) {
        int ps[E_ELEM + 1];
        int s = 0;
        for (int e = 0; e < E_ELEM; ++e) {
            ps[e] = s;
            cur[e] = s;
            s += ((h[e] + 63) >> 6) << 6;        // 64-align each element range
        }
        ps[E_ELEM] = s;
        int ci = 0;
        for (int e = 0; e < E_ELEM; ++e) {
            for (int ofs = ps[e]; ofs < ps[e + 1]; ofs += CHUNK_J) {
                chE[ci] = e;
                chJ[ci] = ofs;
                chEnd[ci] = ps[e + 1];
                ++ci;
            }
        }
        for (; ci < MAXCHUNK; ++ci) chE[ci] = -1;
    }
    __syncthreads();
    for (int n = tid; n < N_NODES; n += 1024) {
        int e = elem[n];
        int pos = atomicAdd(&cur[e], 1);
        jlist[pos] = n;
    }
}

// Fused mid: blocks <1280 fold P[e,c]; blocks >=1280 transpose x into sorted
// j-space with GATHER reads / COALESCED writes (R8 version scattered 36 B
// writes -> partial-line RMW; reads absorb in L2/L3 instead). Pad j -> 0.
__global__ __launch_bounds__(256) void k_mid(
    const float* __restrict__ S31, const float* __restrict__ S30,
    const float* __restrict__ S21, const float* __restrict__ S20,
    const float* __restrict__ U1_1, const float* __restrict__ U1_0,
    const float* __restrict__ W3_1, const float* __restrict__ W3_0,
    const float* __restrict__ W2_1, const float* __restrict__ W2_0,
    const float* __restrict__ W1_1, const float* __restrict__ W1_0,
    float* __restrict__ P,
    const float* __restrict__ x, const int* __restrict__ jlist,
    float* __restrict__ xs) {
    int bid = blockIdx.x;
    if (bid >= 1280) {
        int t = (bid - 1280) * 256 + threadIdx.x;   // [0, 128*4736*9) exact
        int i = t % 9;
        int r = t / 9;
        int j = r % NP;
        int c = r / NP;
        int n = jlist[j];
        xs[t] = (n >= 0) ? x[((size_t)n * C_CH + c) * 9 + i] : 0.f;
        return;
    }
    int e = bid >> 7;
    int c = bid & 127;
    float* Pout = P + (size_t)bid * PSTRIDE;
    for (int q = threadIdx.x; q < PSTRIDE; q += 256) {
        int t = q >> 2, m = q & 3;
        float v;
        if (t < 9) {
            int a = t;
            v = (m == 0) ? U1_0[a] * W1_0[e * C_CH + c]
                         : U1_1[(m - 1) * 9 + a] * W1_1[e * C_CH + c];
        } else if (t < 54) {
            int t2 = t - 9;
            float s = 0.f;
            if (m == 0) {
#pragma unroll
                for (int p = 0; p < 2; ++p)
                    s = fmaf(S20[t2 * 2 + p], W2_0[(e * 2 + p) * C_CH + c], s);
            } else {
#pragma unroll
                for (int p = 0; p < 3; ++p)
                    s = fmaf(S21[((m - 1) * 45 + t2) * 3 + p], W2_1[(e * 3 + p) * C_CH + c], s);
            }
            v = s;
        } else {
            int t3 = t - 54;
            float s = 0.f;
            if (m == 0) {
#pragma unroll
                for (int p = 0; p < 5; ++p)
                    s = fmaf(S30[t3 * 5 + p], W3_0[(e * 5 + p) * C_CH + c], s);
            } else {
#pragma unroll
                for (int p = 0; p < 7; ++p)
                    s = fmaf(S31[((m - 1) * 165 + t3) * 7 + p], W3_1[(e * 7 + p) * C_CH + c], s);
            }
            v = s;
        }
        Pout[q] = v;
    }
}

// 219-monomial cubic; coefficients via provably-uniform global addresses ->
// s_load through the constant cache (SGPR operands of v_fma, zero DS/VMEM
// vector traffic for coefficients). sched_barrier(0) per (a,b) group: <=10
// float4 scalar loads (40 SGPRs) in flight.
__device__ __forceinline__ void poly_eval1(const float* __restrict__ sP,
                                           const float (&xv)[9], float (&acc)[4]) {
    const float* p1 = sP;
    const float* p2 = sP + 9 * 4;
    const float* p3 = sP + 54 * 4;
    int i2 = 0, i3 = 0;
#pragma unroll
    for (int a = 0; a < 9; ++a) {
        float4 q1 = *(const float4*)(p1 + a * 4);
        float xa = xv[a];
        acc[0] = fmaf(q1.x, xa, acc[0]);
        acc[1] = fmaf(q1.y, xa, acc[1]);
        acc[2] = fmaf(q1.z, xa, acc[2]);
        acc[3] = fmaf(q1.w, xa, acc[3]);
        __builtin_amdgcn_sched_barrier(0);
#pragma unroll
        for (int b = a; b < 9; ++b) {
            float4 q2 = *(const float4*)(p2 + i2 * 4);
            ++i2;
            float m2 = xv[a] * xv[b];
            acc[0] = fmaf(q2.x, m2, acc[0]);
            acc[1] = fmaf(q2.y, m2, acc[1]);
            acc[2] = fmaf(q2.z, m2, acc[2]);
            acc[3] = fmaf(q2.w, m2, acc[3]);
#pragma unroll
            for (int i = b; i < 9; ++i) {
                float4 q3 = *(const float4*)(p3 + i3 * 4);
                ++i3;
                float m3 = m2 * xv[i];
                acc[0] = fmaf(q3.x, m3, acc[0]);
                acc[1] = fmaf(q3.y, m3, acc[1]);
                acc[2] = fmaf(q3.z, m3, acc[2]);
                acc[3] = fmaf(q3.w, m3, acc[3]);
            }
            __builtin_amdgcn_sched_barrier(0);
        }
    }
}

__global__ __launch_bounds__(256) void k_poly(
    const float* __restrict__ xs, const int* __restrict__ chE,
    const int* __restrict__ chJ, const int* __restrict__ chEnd,
    const float* __restrict__ P, float* __restrict__ bout) {
    int ci = blockIdx.y;
    int e = chE[ci];
    if (e < 0) return;
    e = __builtin_amdgcn_readfirstlane(e);
    int c = blockIdx.x;
    const float* __restrict__ Pg = P + (size_t)(e * C_CH + c) * PSTRIDE;

    const int end = chEnd[ci];
    const int j = chJ[ci] + threadIdx.x;
    if (j >= end) return;

    float xv[9];
    const float* px = xs + ((size_t)c * NP + j) * 9;   // coalesced
#pragma unroll
    for (int i = 0; i < 9; ++i) xv[i] = px[i];
    float acc[4] = {};
    poly_eval1(Pg, xv, acc);
#pragma unroll
    for (int m = 0; m < 4; ++m) bout[(size_t)(c * 4 + m) * NP + j] = acc[m];
}

// j-lane GEMM v4: one block covers ALL 128 d of a slot -> bout read exactly
// once (R8 read it 4x = 39 MB). 512 thr: jj=tid&63 (coalesced bout), wave
// wv=tid>>6 owns 16 d (readfirstlane -> s_load_dwordx16 W rows). 16-deep bv
// batches, 256 FMA per latency round.
__global__ __launch_bounds__(512) void k_linear(
    const float* __restrict__ bout, const int* __restrict__ jlist,
    const float* __restrict__ Wl0, const float* __restrict__ Wl1,
    const float* __restrict__ sc, float* __restrict__ out) {
    const int s  = blockIdx.y;                       // slot 0..3
    const int jj = threadIdx.x & 63;
    const int wv = threadIdx.x >> 6;                 // 0..7
    const int dbase = __builtin_amdgcn_readfirstlane(wv * 16);
    const int j = blockIdx.x * 64 + jj;
    const float* __restrict__ Wl = (s == 0) ? Wl0 : Wl1;
    const float* __restrict__ brow = bout + (size_t)s * NP + j;

    float acc[16];
#pragma unroll
    for (int k = 0; k < 16; ++k) acc[k] = 0.f;

#pragma unroll 1
    for (int cc0 = 0; cc0 < C_CH; cc0 += 16) {
        float bv[16];
#pragma unroll
        for (int t = 0; t < 16; ++t)
            bv[t] = brow[(size_t)(cc0 + t) * 4 * NP];
#pragma unroll
        for (int t = 0; t < 16; ++t) {
            const float* wrow = Wl + (cc0 + t) * C_CH + dbase;  // scalar addr
#pragma unroll
            for (int k = 0; k < 16; ++k) acc[k] = fmaf(bv[t], wrow[k], acc[k]);
        }
    }

    const int n = jlist[j];
    if (n < 0) return;
    const float inv = 0.08838834764831845f;  // 1/sqrt(128)
#pragma unroll
    for (int k = 0; k < 16; ++k) {
        int d = dbase + k;
        int col = (s == 0) ? d : (128 + d * 3 + (s - 1));
        out[n * 512 + col] = fmaf(acc[k], inv, sc[n * 512 + col]);
    }
}

extern "C" void kernel_launch(void* const* d_in, const int* in_sizes, int n_in,
                              void* d_out, int out_size, void* d_ws, size_t ws_size,
                              hipStream_t stream) {
    const float* x     = (const float*)d_in[0];
    const float* sc    = (const float*)d_in[1];
    const float* attrs = (const float*)d_in[2];
    const float* U3_0 = (const float*)d_in[3];
    const float* U2_0 = (const float*)d_in[4];
    const float* U1_0 = (const float*)d_in[5];
    const float* W3_0 = (const float*)d_in[6];
    const float* W2_0 = (const float*)d_in[7];
    const float* W1_0 = (const float*)d_in[8];
    const float* Wl0  = (const float*)d_in[9];
    const float* U3_1 = (const float*)d_in[10];
    const float* U2_1 = (const float*)d_in[11];
    const float* U1_1 = (const float*)d_in[12];
    const float* W3_1 = (const float*)d_in[13];
    const float* W2_1 = (const float*)d_in[14];
    const float* W1_1 = (const float*)d_in[15];
    const float* Wl1  = (const float*)d_in[16];

    char* ws = (char*)d_ws;
    int* chE     = (int*)(ws + WS_CHE);
    int* chJ     = (int*)(ws + WS_CHJ);
    int* chEnd   = (int*)(ws + WS_CHEND);
    int* jlist   = (int*)(ws + WS_JLIST);
    int* elem    = (int*)(ws + WS_ELEM);
    float* S31   = (float*)(ws + WS_S31);
    float* S30   = (float*)(ws + WS_S30);
    float* S21   = (float*)(ws + WS_S21);
    float* S20   = (float*)(ws + WS_S20);
    float* P     = (float*)(ws + WS_P);
    float* bout  = (float*)(ws + WS_BOUT);
    float* xs    = (float*)(ws + WS_XS);

    // L1: sym + elem decode (independent, one dispatch)
    k_front<<<35, 256, 0, stream>>>(attrs, elem, U3_1, U3_0, U2_1, U2_0,
                                    S31, S30, S21, S20);
    // L2: hist + prefix + chunk table + pad fill + scatter (one block)
    k_sort<<<1, 1024, 0, stream>>>(elem, jlist, chE, chJ, chEnd);
    // L3: fold P  ||  transpose x -> xs (coalesced writes)
    k_mid<<<1280 + (C_CH * NP * 9) / 256, 256, 0, stream>>>(
        S31, S30, S21, S20, U1_1, U1_0, W3_1, W3_0, W2_1, W2_0, W1_1, W1_0,
        P, x, jlist, xs);
    // L4: 219-monomial cubic
    k_poly<<<dim3(128, MAXCHUNK), 256, 0, stream>>>(xs, chE, chJ, chEnd, P, bout);
    // L5: channel-mixing linear + residual
    k_linear<<<dim3(NP / 64, 4), 512, 0, stream>>>(bout, jlist, Wl0, Wl1, sc,
                                                   (float*)d_out);
}

// Round 10
// 91.656 us; speedup vs baseline: 9.4552x; 1.1531x over previous
//
#include <hip/hip_runtime.h>

#define N_NODES 4096
#define C_CH    128
#define E_ELEM  10
#define NP      4736          // padded sorted-node space (64-aligned per element)
#define TT      219           // 9 deg1 + 45 deg2 + 165 deg3 monomials
#define PSTRIDE (TT * 4)      // 876 floats per (e,c): [t][m], m0=L0, m1..3=L1
#define MAXCHUNK 32
#define CHUNK_J  256          // j-slots per k_poly block (256 thr x 1 node)

// ws layout (bytes):
#define WS_CHE     256
#define WS_CHJ     512
#define WS_CHEND   768
#define WS_JLIST   1024        // int[4736]
#define WS_ELEM    20480       // int[4096]
#define WS_S31     53248       // float[3465]
#define WS_S30     67136       // float[825]
#define WS_S21     70464       // float[405]
#define WS_S20     72128       // float[90]
#define WS_P       72704       // float[1280*876] = 4485120 B
#define WS_BOUT    4557824     // float[512*4736] = 9699328 B
#define WS_XS      14257152    // float[128*4736*9] = 21823488 B
#define WS_XS_END  36080640ull

__device__ __forceinline__ void t3_decode(int t, int& a, int& b, int& i) {
    int cnt = 0;
    for (int aa = 0; aa < 9; ++aa)
        for (int bb = aa; bb < 9; ++bb) {
            int len = 9 - bb;
            if (t < cnt + len) { a = aa; b = bb; i = bb + (t - cnt); return; }
            cnt += len;
        }
    a = b = i = 8;
}

__device__ __forceinline__ void t2_decode(int t, int& a, int& b) {
    int cnt = 0;
    for (int aa = 0; aa < 9; ++aa) {
        int len = 9 - aa;
        if (t < cnt + len) { a = aa; b = aa + (t - cnt); return; }
        cnt += len;
    }
    a = b = 8;
}

// Fused front: blocks 0-18 symmetrize U (4785 items); blocks 19-34 decode
// elem (4096 nodes).
__global__ __launch_bounds__(256) void k_front(
    const float* __restrict__ attrs, int* __restrict__ elem,
    const float* __restrict__ U3_1, const float* __restrict__ U3_0,
    const float* __restrict__ U2_1, const float* __restrict__ U2_0,
    float* __restrict__ S31, float* __restrict__ S30,
    float* __restrict__ S21, float* __restrict__ S20) {
    int bid = blockIdx.x;
    if (bid >= 19) {
        int n = (bid - 19) * 256 + threadIdx.x;
        if (n >= N_NODES) return;
        const float* a = attrs + n * E_ELEM;
        float best = a[0];
        int e = 0;
#pragma unroll
        for (int k = 1; k < E_ELEM; ++k) {
            float v = a[k];
            if (v > best) { best = v; e = k; }
        }
        elem[n] = e;
        return;
    }
    int q = bid * 256 + threadIdx.x;
    if (q < 3465) {                                 // S31 [m][t][p], p=7
        int m = q / 1155, r = q % 1155, t = r / 7, p = r % 7;
        int a, b, i;
        t3_decode(t, a, b, i);
#define U31(X, Y, Z) U3_1[((((m * 9 + (X)) * 9 + (Y)) * 9 + (Z)) * 7) + p]
        float s = U31(a, b, i);
        if (a == b && b == i) {}
        else if (a == b) s += U31(a, i, a) + U31(i, a, a);
        else if (b == i) s += U31(b, a, b) + U31(b, b, a);
        else s += U31(a, i, b) + U31(b, a, i) + U31(b, i, a) + U31(i, a, b) + U31(i, b, a);
#undef U31
        S31[q] = s;
        return;
    }
    q -= 3465;
    if (q < 825) {                                  // S30 [t][p], p=5
        int t = q / 5, p = q % 5;
        int a, b, i;
        t3_decode(t, a, b, i);
#define U30(X, Y, Z) U3_0[((((X) * 9 + (Y)) * 9 + (Z)) * 5) + p]
        float s = U30(a, b, i);
        if (a == b && b == i) {}
        else if (a == b) s += U30(a, i, a) + U30(i, a, a);
        else if (b == i) s += U30(b, a, b) + U30(b, b, a);
        else s += U30(a, i, b) + U30(b, a, i) + U30(b, i, a) + U30(i, a, b) + U30(i, b, a);
#undef U30
        S30[q] = s;
        return;
    }
    q -= 825;
    if (q < 405) {                                  // S21 [m][t][p], p=3
        int m = q / 135, r = q % 135, t = r / 3, p = r % 3;
        int a, b;
        t2_decode(t, a, b);
        float s = U2_1[(((m * 9 + a) * 9 + b) * 3) + p];
        if (a != b) s += U2_1[(((m * 9 + b) * 9 + a) * 3) + p];
        S21[q] = s;
        return;
    }
    q -= 405;
    if (q < 90) {                                   // S20 [t][p], p=2
        int t = q / 2, p = q % 2;
        int a, b;
        t2_decode(t, a, b);
        float s = U2_0[((a * 9 + b) * 2) + p];
        if (a != b) s += U2_0[((b * 9 + a) * 2) + p];
        S20[q] = s;
    }
}

// Single-block sort: LDS histogram -> prefix -> chunk table -> jlist pad-fill
// -> LDS-cursor scatter.
__global__ __launch_bounds__(1024) void k_sort(
    const int* __restrict__ elem, int* __restrict__ jlist,
    int* __restrict__ chE, int* __restrict__ chJ, int* __restrict__ chEnd) {
    __shared__ int h[E_ELEM];
    __shared__ int cur[E_ELEM];
    int tid = threadIdx.x;
    if (tid < E_ELEM) h[tid] = 0;
    __syncthreads();
    for (int n = tid; n < N_NODES; n += 1024) atomicAdd(&h[elem[n]], 1);
    for (int p = tid; p < NP; p += 1024) jlist[p] = -1;
    __syncthreads();
    if (tid == 0) {
        int ps[E_ELEM + 1];
        int s = 0;
        for (int e = 0; e < E_ELEM; ++e) {
            ps[e] = s;
            cur[e] = s;
            s += ((h[e] + 63) >> 6) << 6;        // 64-align each element range
        }
        ps[E_ELEM] = s;
        int ci = 0;
        for (int e = 0; e < E_ELEM; ++e) {
            for (int ofs = ps[e]; ofs < ps[e + 1]; ofs += CHUNK_J) {
                chE[ci] = e;
                chJ[ci] = ofs;
                chEnd[ci] = ps[e + 1];
                ++ci;
            }
        }
        for (; ci < MAXCHUNK; ++ci) chE[ci] = -1;
    }
    __syncthreads();
    for (int n = tid; n < N_NODES; n += 1024) {
        int e = elem[n];
        int pos = atomicAdd(&cur[e], 1);
        jlist[pos] = n;
    }
}

// Fused mid: blocks <1280 fold P[e,c]; blocks >=1280 transpose x into sorted
// j-space (gather reads / coalesced writes). Pad j -> 0.
__global__ __launch_bounds__(256) void k_mid(
    const float* __restrict__ S31, const float* __restrict__ S30,
    const float* __restrict__ S21, const float* __restrict__ S20,
    const float* __restrict__ U1_1, const float* __restrict__ U1_0,
    const float* __restrict__ W3_1, const float* __restrict__ W3_0,
    const float* __restrict__ W2_1, const float* __restrict__ W2_0,
    const float* __restrict__ W1_1, const float* __restrict__ W1_0,
    float* __restrict__ P,
    const float* __restrict__ x, const int* __restrict__ jlist,
    float* __restrict__ xs) {
    int bid = blockIdx.x;
    if (bid >= 1280) {
        int t = (bid - 1280) * 256 + threadIdx.x;   // [0, 128*4736*9) exact
        int i = t % 9;
        int r = t / 9;
        int j = r % NP;
        int c = r / NP;
        int n = jlist[j];
        xs[t] = (n >= 0) ? x[((size_t)n * C_CH + c) * 9 + i] : 0.f;
        return;
    }
    int e = bid >> 7;
    int c = bid & 127;
    float* Pout = P + (size_t)bid * PSTRIDE;
    for (int q = threadIdx.x; q < PSTRIDE; q += 256) {
        int t = q >> 2, m = q & 3;
        float v;
        if (t < 9) {
            int a = t;
            v = (m == 0) ? U1_0[a] * W1_0[e * C_CH + c]
                         : U1_1[(m - 1) * 9 + a] * W1_1[e * C_CH + c];
        } else if (t < 54) {
            int t2 = t - 9;
            float s = 0.f;
            if (m == 0) {
#pragma unroll
                for (int p = 0; p < 2; ++p)
                    s = fmaf(S20[t2 * 2 + p], W2_0[(e * 2 + p) * C_CH + c], s);
            } else {
#pragma unroll
                for (int p = 0; p < 3; ++p)
                    s = fmaf(S21[((m - 1) * 45 + t2) * 3 + p], W2_1[(e * 3 + p) * C_CH + c], s);
            }
            v = s;
        } else {
            int t3 = t - 54;
            float s = 0.f;
            if (m == 0) {
#pragma unroll
                for (int p = 0; p < 5; ++p)
                    s = fmaf(S30[t3 * 5 + p], W3_0[(e * 5 + p) * C_CH + c], s);
            } else {
#pragma unroll
                for (int p = 0; p < 7; ++p)
                    s = fmaf(S31[((m - 1) * 165 + t3) * 7 + p], W3_1[(e * 7 + p) * C_CH + c], s);
            }
            v = s;
        }
        Pout[q] = v;
    }
}

// 219-monomial cubic; coefficients via provably-uniform global addresses ->
// s_load through the constant cache. sched_barrier(0) per (a,b) group.
__device__ __forceinline__ void poly_eval1(const float* __restrict__ sP,
                                           const float (&xv)[9], float (&acc)[4]) {
    const float* p1 = sP;
    const float* p2 = sP + 9 * 4;
    const float* p3 = sP + 54 * 4;
    int i2 = 0, i3 = 0;
#pragma unroll
    for (int a = 0; a < 9; ++a) {
        float4 q1 = *(const float4*)(p1 + a * 4);
        float xa = xv[a];
        acc[0] = fmaf(q1.x, xa, acc[0]);
        acc[1] = fmaf(q1.y, xa, acc[1]);
        acc[2] = fmaf(q1.z, xa, acc[2]);
        acc[3] = fmaf(q1.w, xa, acc[3]);
        __builtin_amdgcn_sched_barrier(0);
#pragma unroll
        for (int b = a; b < 9; ++b) {
            float4 q2 = *(const float4*)(p2 + i2 * 4);
            ++i2;
            float m2 = xv[a] * xv[b];
            acc[0] = fmaf(q2.x, m2, acc[0]);
            acc[1] = fmaf(q2.y, m2, acc[1]);
            acc[2] = fmaf(q2.z, m2, acc[2]);
            acc[3] = fmaf(q2.w, m2, acc[3]);
#pragma unroll
            for (int i = b; i < 9; ++i) {
                float4 q3 = *(const float4*)(p3 + i3 * 4);
                ++i3;
                float m3 = m2 * xv[i];
                acc[0] = fmaf(q3.x, m3, acc[0]);
                acc[1] = fmaf(q3.y, m3, acc[1]);
                acc[2] = fmaf(q3.z, m3, acc[2]);
                acc[3] = fmaf(q3.w, m3, acc[3]);
            }
            __builtin_amdgcn_sched_barrier(0);
        }
    }
}

__global__ __launch_bounds__(256) void k_poly(
    const float* __restrict__ xs, const int* __restrict__ chE,
    const int* __restrict__ chJ, const int* __restrict__ chEnd,
    const float* __restrict__ P, float* __restrict__ bout) {
    int ci = blockIdx.y;
    int e = chE[ci];
    if (e < 0) return;
    e = __builtin_amdgcn_readfirstlane(e);
    int c = blockIdx.x;
    const float* __restrict__ Pg = P + (size_t)(e * C_CH + c) * PSTRIDE;

    const int end = chEnd[ci];
    const int j = chJ[ci] + threadIdx.x;
    if (j >= end) return;

    float xv[9];
    const float* px = xs + ((size_t)c * NP + j) * 9;   // coalesced
#pragma unroll
    for (int i = 0; i < 9; ++i) xv[i] = px[i];
    float acc[4] = {};
    poly_eval1(Pg, xv, acc);
#pragma unroll
    for (int m = 0; m < 4; ++m) bout[(size_t)(c * 4 + m) * NP + j] = acc[m];
}

// j-lane GEMM v5. R8's v4 (296 blocks, all-d-per-block) regressed to 50 us:
// 1.2 blocks/CU (occ 16%) + 16x s_load_dwordx16 per batch (256 SGPRs)
// serialized on SGPR pressure. Revert to the R7 shape — grid (74,16) = 1184
// blocks (18 waves/CU), D=8 d/thread (2 s_load_dwordx4 of W per t, no SGPR
// cliff) — and widen the bv batch 16 -> 32 (VGPR ~52, under the 64-reg/
// 8-wave ceiling): 32 coalesced loads in flight = 2 full L2 latencies
// covered, 256 FMA per round. bout read 4x (39 MB) is ~6 us of BW — cheap
// vs the 30+ us of exposed latency v4 paid.
__global__ __launch_bounds__(256) void k_linear(
    const float* __restrict__ bout, const int* __restrict__ jlist,
    const float* __restrict__ Wl0, const float* __restrict__ Wl1,
    const float* __restrict__ sc, float* __restrict__ out) {
    const int s  = blockIdx.y >> 2;
    const int dg = blockIdx.y & 3;
    const int jj = threadIdx.x & 63;
    const int wv = threadIdx.x >> 6;
    const int dbase = __builtin_amdgcn_readfirstlane(dg * 32 + wv * 8);
    const int j = blockIdx.x * 64 + jj;
    const float* __restrict__ Wl = (s == 0) ? Wl0 : Wl1;
    const float* __restrict__ brow = bout + (size_t)s * NP + j;

    float acc[8];
#pragma unroll
    for (int k = 0; k < 8; ++k) acc[k] = 0.f;

#pragma unroll 1
    for (int cc0 = 0; cc0 < C_CH; cc0 += 32) {
        float bv[32];
#pragma unroll
        for (int t = 0; t < 32; ++t)
            bv[t] = brow[(size_t)(cc0 + t) * 4 * NP];
#pragma unroll
        for (int t = 0; t < 32; ++t) {
            const float* wrow = Wl + (cc0 + t) * C_CH + dbase;  // scalar addr
#pragma unroll
            for (int k = 0; k < 8; ++k) acc[k] = fmaf(bv[t], wrow[k], acc[k]);
        }
    }

    const int n = jlist[j];
    if (n < 0) return;
    const float inv = 0.08838834764831845f;  // 1/sqrt(128)
#pragma unroll
    for (int k = 0; k < 8; ++k) {
        int d = dbase + k;
        int col = (s == 0) ? d : (128 + d * 3 + (s - 1));
        out[n * 512 + col] = fmaf(acc[k], inv, sc[n * 512 + col]);
    }
}

extern "C" void kernel_launch(void* const* d_in, const int* in_sizes, int n_in,
                              void* d_out, int out_size, void* d_ws, size_t ws_size,
                              hipStream_t stream) {
    const float* x     = (const float*)d_in[0];
    const float* sc    = (const float*)d_in[1];
    const float* attrs = (const float*)d_in[2];
    const float* U3_0 = (const float*)d_in[3];
    const float* U2_0 = (const float*)d_in[4];
    const float* U1_0 = (const float*)d_in[5];
    const float* W3_0 = (const float*)d_in[6];
    const float* W2_0 = (const float*)d_in[7];
    const float* W1_0 = (const float*)d_in[8];
    const float* Wl0  = (const float*)d_in[9];
    const float* U3_1 = (const float*)d_in[10];
    const float* U2_1 = (const float*)d_in[11];
    const float* U1_1 = (const float*)d_in[12];
    const float* W3_1 = (const float*)d_in[13];
    const float* W2_1 = (const float*)d_in[14];
    const float* W1_1 = (const float*)d_in[15];
    const float* Wl1  = (const float*)d_in[16];

    char* ws = (char*)d_ws;
    int* chE     = (int*)(ws + WS_CHE);
    int* chJ     = (int*)(ws + WS_CHJ);
    int* chEnd   = (int*)(ws + WS_CHEND);
    int* jlist   = (int*)(ws + WS_JLIST);
    int* elem    = (int*)(ws + WS_ELEM);
    float* S31   = (float*)(ws + WS_S31);
    float* S30   = (float*)(ws + WS_S30);
    float* S21   = (float*)(ws + WS_S21);
    float* S20   = (float*)(ws + WS_S20);
    float* P     = (float*)(ws + WS_P);
    float* bout  = (float*)(ws + WS_BOUT);
    float* xs    = (float*)(ws + WS_XS);

    // L1: sym + elem decode (independent, one dispatch)
    k_front<<<35, 256, 0, stream>>>(attrs, elem, U3_1, U3_0, U2_1, U2_0,
                                    S31, S30, S21, S20);
    // L2: hist + prefix + chunk table + pad fill + scatter (one block)
    k_sort<<<1, 1024, 0, stream>>>(elem, jlist, chE, chJ, chEnd);
    // L3: fold P  ||  transpose x -> xs (coalesced writes)
    k_mid<<<1280 + (C_CH * NP * 9) / 256, 256, 0, stream>>>(
        S31, S30, S21, S20, U1_1, U1_0, W3_1, W3_0, W2_1, W2_0, W1_1, W1_0,
        P, x, jlist, xs);
    // L4: 219-monomial cubic
    k_poly<<<dim3(128, MAXCHUNK), 256, 0, stream>>>(xs, chE, chJ, chEnd, P, bout);
    // L5: channel-mixing linear + residual
    k_linear<<<dim3(NP / 64, 16), 256, 0, stream>>>(bout, jlist, Wl0, Wl1, sc,
                                                    (float*)d_out);
}